// Round 1
// baseline (4803.640 us; speedup 1.0000x reference)
//
#include <hip/hip_runtime.h>
#include <math.h>

namespace {

constexpr int BATCH = 32;
constexpr int SEQ   = 512;
constexpr int DIN   = 9;
constexpr int EMB   = 256;
constexpr int FF    = 1024;
constexpr int NLAYER= 4;
constexpr int NCLS  = 10;
constexpr int NHEADS= 8;
constexpr int HDIM  = 32;
constexpr int NTOK  = BATCH*SEQ;      // 16384
constexpr int FFCH  = 4096;           // FFN row chunk

// ---------------- generic fp32 GEMM:  C[M,N] = A[M,K] @ W[N,K]^T + bias ----------------
template<bool RELU>
__global__ void gemm_bias(const float* __restrict__ A, int lda,
                          const float* __restrict__ W,
                          const float* __restrict__ bias,
                          float* __restrict__ Co, int ldc,
                          int M, int N, int K)
{
    __shared__ float As[16][65];
    __shared__ float Bs[16][65];
    const int bm = blockIdx.y*64, bn = blockIdx.x*64;
    const int tx = threadIdx.x, ty = threadIdx.y;   // 16x16
    const int tid = ty*16+tx;
    float acc[4][4] = {};
    for (int k0 = 0; k0 < K; k0 += 16) {
        #pragma unroll
        for (int i = 0; i < 4; i++) {
            int idx = i*256 + tid;
            int r = idx >> 4, kk = idx & 15;
            As[kk][r] = (bm+r < M) ? A[(size_t)(bm+r)*lda + k0+kk] : 0.f;
            Bs[kk][r] = (bn+r < N) ? W[(size_t)(bn+r)*K  + k0+kk] : 0.f;
        }
        __syncthreads();
        #pragma unroll
        for (int k = 0; k < 16; k++) {
            float a[4], b[4];
            #pragma unroll
            for (int i = 0; i < 4; i++) a[i] = As[k][ty*4+i];
            #pragma unroll
            for (int j = 0; j < 4; j++) b[j] = Bs[k][tx*4+j];
            #pragma unroll
            for (int i = 0; i < 4; i++)
                #pragma unroll
                for (int j = 0; j < 4; j++)
                    acc[i][j] += a[i]*b[j];
        }
        __syncthreads();
    }
    #pragma unroll
    for (int i = 0; i < 4; i++) {
        int m = bm + ty*4 + i; if (m >= M) continue;
        #pragma unroll
        for (int j = 0; j < 4; j++) {
            int n = bn + tx*4 + j; if (n >= N) continue;
            float v = acc[i][j] + bias[n];
            if (RELU) v = fmaxf(v, 0.f);
            Co[(size_t)m*ldc + n] = v;
        }
    }
}

// ---------------- embed + scale + sinusoidal positional encoding ----------------
__global__ void embed_kernel(const float* __restrict__ src,
                             const float* __restrict__ emb_W,
                             const float* __restrict__ emb_b,
                             float* __restrict__ x)
{
    int row = blockIdx.x;            // token = b*SEQ + s
    int e = threadIdx.x;             // 0..255
    int s = row % SEQ;
    const float* sr = src + (size_t)row*DIN;
    float acc = emb_b[e];
    #pragma unroll
    for (int d = 0; d < DIN; d++) acc += sr[d]*emb_W[e*DIN + d];
    acc *= 16.0f;                    // sqrt(EMB)
    int i2 = e & ~1;
    float div = expf(-(float)i2 * (9.210340371976184f / (float)EMB)); // ln(10000)
    float ang = (float)s * div;
    float pe = (e & 1) ? cosf(ang) : sinf(ang);
    x[(size_t)row*EMB + e] = acc + pe;
}

// ---------------- gather last-token rows ----------------
__global__ void pack_last(const float* __restrict__ x, float* __restrict__ xl)
{
    int b = blockIdx.x, e = threadIdx.x;
    xl[b*EMB + e] = x[((size_t)b*SEQ + SEQ-1)*EMB + e];
}

// ---------------- last-row attention: softmax over k != S-1, o_last, head-avg ----------------
// kv layout: [B*S, 512], cols 0..255 = k, 256..511 = v. Writes o_last into v last row.
__global__ void attn_last(const float* __restrict__ ql,   // [B,256]
                          float* __restrict__ kv,
                          float* __restrict__ amL)        // [B,SEQ] for this layer
{
    int b = blockIdx.x;
    int t = threadIdx.x;             // 0..511
    __shared__ float sc[NHEADS][SEQ];
    float* kvb = kv + (size_t)b*SEQ*512;

    // scores for each head
    #pragma unroll
    for (int h = 0; h < NHEADS; h++) {
        const float* qh = ql + b*EMB + h*HDIM;
        const float* kh = kvb + (size_t)t*512 + h*HDIM;
        float s = 0.f;
        #pragma unroll
        for (int d = 0; d < HDIM; d++) s += qh[d]*kh[d];
        s *= 0.17677669529663687f;   // 1/sqrt(32)
        if (t == SEQ-1) s += -1e9f;  // mask: last row can't attend to itself
        sc[h][t] = s;
    }
    __syncthreads();

    // per-head softmax: wave w handles head w (512 threads = 8 waves)
    {
        int w = t >> 6, lane = t & 63;
        float pv[SEQ/64];
        float m = -1e30f;
        #pragma unroll
        for (int j = 0; j < SEQ/64; j++) { pv[j] = sc[w][lane + j*64]; m = fmaxf(m, pv[j]); }
        #pragma unroll
        for (int o = 32; o; o >>= 1) m = fmaxf(m, __shfl_xor(m, o));
        float ssum = 0.f;
        #pragma unroll
        for (int j = 0; j < SEQ/64; j++) { pv[j] = expf(pv[j] - m); ssum += pv[j]; }
        #pragma unroll
        for (int o = 32; o; o >>= 1) ssum += __shfl_xor(ssum, o);
        float inv = 1.f/ssum;
        #pragma unroll
        for (int j = 0; j < SEQ/64; j++) sc[w][lane + j*64] = pv[j]*inv;
    }
    __syncthreads();

    // head-averaged attention row for this layer's attns output
    {
        float a = 0.f;
        #pragma unroll
        for (int h = 0; h < NHEADS; h++) a += sc[h][t];
        amL[b*SEQ + t] = a * 0.125f;
    }

    // o_last[e] = sum_t a[h(e)][t] * v[t][e];  overwrite v last row (each thread
    // reads/writes only its own column e -> no cross-thread hazard)
    if (t < EMB) {
        int h = t >> 5;
        float o = 0.f;
        for (int k = 0; k < SEQ; k++) o += sc[h][k] * kvb[(size_t)k*512 + 256 + t];
        kvb[(size_t)(SEQ-1)*512 + 256 + t] = o;
    }
}

// ---------------- residual + layernorm (in-place on x) ----------------
__global__ void resln(float* __restrict__ x, const float* __restrict__ t,
                      const float* __restrict__ g, const float* __restrict__ bb)
{
    int row = blockIdx.x;
    int e = threadIdx.x;             // 256 threads = 4 waves
    __shared__ float red1[4], red2[4];
    float v = x[(size_t)row*EMB + e] + t[(size_t)row*EMB + e];
    float s = v;
    #pragma unroll
    for (int o = 32; o; o >>= 1) s += __shfl_xor(s, o);
    if ((e & 63) == 0) red1[e >> 6] = s;
    __syncthreads();
    float mean = (red1[0]+red1[1]+red1[2]+red1[3]) * (1.f/EMB);
    float d = v - mean;
    float s2 = d*d;
    #pragma unroll
    for (int o = 32; o; o >>= 1) s2 += __shfl_xor(s2, o);
    if ((e & 63) == 0) red2[e >> 6] = s2;
    __syncthreads();
    float var = (red2[0]+red2[1]+red2[2]+red2[3]) * (1.f/EMB);
    x[(size_t)row*EMB + e] = d * (1.f/sqrtf(var + 1e-5f)) * g[e] + bb[e];
}

// ---------------- write full attns output [L,B,S,S] ----------------
__global__ void write_attns(float* __restrict__ attns, const float* __restrict__ am_all)
{
    constexpr int PER_ROW = SEQ/4;   // 128 float4 per row
    size_t tid = (size_t)blockIdx.x*blockDim.x + threadIdx.x;
    size_t row = tid / PER_ROW;      // l*B*S + b*S + q
    int c4 = (int)(tid % PER_ROW);
    int q = (int)(row % SEQ);
    float4 v = make_float4(0.f,0.f,0.f,0.f);
    if (q == SEQ-1) {
        size_t lb = row / SEQ;       // l*B + b
        const float* amr = am_all + lb*SEQ + c4*4;
        v = make_float4(amr[0], amr[1], amr[2], amr[3]);
    } else if ((q >> 2) == c4) {
        ((float*)&v)[q & 3] = 1.f;
    }
    ((float4*)attns)[tid] = v;
}

// ---------------- final: r[b,e] = sum_s relu(x[b,s,e]) ----------------
__global__ void reduce_relu(const float* __restrict__ x, float* __restrict__ r)
{
    int b = blockIdx.x, e = threadIdx.x;
    const float* xb = x + (size_t)b*SEQ*EMB;
    float s = 0.f;
    for (int i = 0; i < SEQ; i++) s += fmaxf(xb[(size_t)i*EMB + e], 0.f);
    r[b*EMB + e] = s;
}

// ---------------- decode + log_softmax ----------------
__global__ void decode_out(const float* __restrict__ r, const float* __restrict__ dec_W,
                           float* __restrict__ out)
{
    __shared__ float logits[BATCH][NCLS];
    int tid = threadIdx.x;
    if (tid < BATCH*NCLS) {
        int b = tid / NCLS, c = tid % NCLS;
        float acc = 0.f;
        for (int e = 0; e < EMB; e++) acc += r[b*EMB + e]*dec_W[c*EMB + e];
        logits[b][c] = acc * (1.f/(float)SEQ);
    }
    __syncthreads();
    if (tid < BATCH) {
        float m = -1e30f;
        #pragma unroll
        for (int c = 0; c < NCLS; c++) m = fmaxf(m, logits[tid][c]);
        float s = 0.f;
        #pragma unroll
        for (int c = 0; c < NCLS; c++) s += expf(logits[tid][c] - m);
        float ls = logf(s);
        #pragma unroll
        for (int c = 0; c < NCLS; c++) out[tid*NCLS + c] = logits[tid][c] - m - ls;
    }
}

} // namespace

extern "C" void kernel_launch(void* const* d_in, const int* in_sizes, int n_in,
                              void* d_out, int out_size, void* d_ws, size_t ws_size,
                              hipStream_t stream)
{
    const float* src   = (const float*)d_in[0];
    const float* emb_W = (const float*)d_in[1];
    const float* emb_b = (const float*)d_in[2];
    const float* Wqkv  = (const float*)d_in[3];
    const float* bqkv  = (const float*)d_in[4];
    const float* Wo    = (const float*)d_in[5];
    const float* bo    = (const float*)d_in[6];
    const float* ln1_g = (const float*)d_in[7];
    const float* ln1_b = (const float*)d_in[8];
    const float* ln2_g = (const float*)d_in[9];
    const float* ln2_b = (const float*)d_in[10];
    const float* W1    = (const float*)d_in[11];
    const float* b1    = (const float*)d_in[12];
    const float* W2    = (const float*)d_in[13];
    const float* b2    = (const float*)d_in[14];
    const float* dec_W = (const float*)d_in[15];

    float* out   = (float*)d_out;               // [32,10]
    float* attns = out + BATCH*NCLS;            // [4,32,512,512]

    // workspace layout
    float* xbuf  = (float*)d_ws;                // [16384,256]
    float* kv    = xbuf + (size_t)NTOK*EMB;     // [16384,512] (k|v)
    float* tbuf  = kv   + (size_t)NTOK*512;     // [16384,256]
    float* hbuf  = tbuf + (size_t)NTOK*EMB;     // [4096,1024] ffn chunk
    float* xl    = hbuf + (size_t)FFCH*FF;      // [32,256]
    float* ql    = xl   + BATCH*EMB;            // [32,256]
    float* amall = ql   + BATCH*EMB;            // [4,32,512]
    float* rbuf  = amall + NLAYER*BATCH*SEQ;    // [32,256]

    dim3 gblk(16,16);

    // embed + pos enc
    embed_kernel<<<NTOK, EMB, 0, stream>>>(src, emb_W, emb_b, xbuf);

    for (int l = 0; l < NLAYER; l++) {
        const float* Wl  = Wqkv + (size_t)l*3*EMB*EMB;
        const float* bl  = bqkv + (size_t)l*3*EMB;

        // gather last-token rows, q for last tokens only
        pack_last<<<BATCH, EMB, 0, stream>>>(xbuf, xl);
        gemm_bias<false><<<dim3(EMB/64, 1), gblk, 0, stream>>>(
            xl, EMB, Wl, bl, ql, EMB, BATCH, EMB, EMB);

        // k,v for all tokens: W rows [E..3E) of Wqkv[l]
        gemm_bias<false><<<dim3(512/64, NTOK/64), gblk, 0, stream>>>(
            xbuf, EMB, Wl + (size_t)EMB*EMB, bl + EMB, kv, 512, NTOK, 512, EMB);

        // last-row attention (writes head-avg row + replaces v last row with o_last)
        attn_last<<<BATCH, SEQ, 0, stream>>>(ql, kv, amall + (size_t)l*BATCH*SEQ);

        // o @ Wo^T + bo   (o == v with last row replaced)
        gemm_bias<false><<<dim3(EMB/64, NTOK/64), gblk, 0, stream>>>(
            kv + 256, 512, Wo + (size_t)l*EMB*EMB, bo + l*EMB, tbuf, EMB, NTOK, EMB, EMB);

        resln<<<NTOK, EMB, 0, stream>>>(xbuf, tbuf, ln1_g + l*EMB, ln1_b + l*EMB);

        // FFN in row chunks
        for (int ch = 0; ch < NTOK; ch += FFCH) {
            gemm_bias<true><<<dim3(FF/64, FFCH/64), gblk, 0, stream>>>(
                xbuf + (size_t)ch*EMB, EMB, W1 + (size_t)l*FF*EMB, b1 + l*FF,
                hbuf, FF, FFCH, FF, EMB);
            gemm_bias<false><<<dim3(EMB/64, FFCH/64), gblk, 0, stream>>>(
                hbuf, FF, W2 + (size_t)l*EMB*FF, b2 + l*EMB,
                tbuf + (size_t)ch*EMB, EMB, FFCH, EMB, FF);
        }
        resln<<<NTOK, EMB, 0, stream>>>(xbuf, tbuf, ln2_g + l*EMB, ln2_b + l*EMB);
    }

    // attns output: zeros + diagonal ones + real last rows
    {
        size_t total_f4 = (size_t)NLAYER*BATCH*SEQ*(SEQ/4);   // 8388608
        int blocks = (int)((total_f4 + 255)/256);
        write_attns<<<blocks, 256, 0, stream>>>(attns, amall);
    }

    // decode
    reduce_relu<<<BATCH, EMB, 0, stream>>>(xbuf, rbuf);
    decode_out<<<1, 384, 0, stream>>>(rbuf, dec_W, out);
}

// Round 3
// 1075.260 us; speedup vs baseline: 4.4674x; 4.4674x over previous
//
#include <hip/hip_runtime.h>
#include <hip/hip_bf16.h>
#include <math.h>

namespace {

constexpr int BATCH = 32;
constexpr int SEQ   = 512;
constexpr int DIN   = 9;
constexpr int EMB   = 256;
constexpr int FF    = 1024;
constexpr int NLAYER= 4;
constexpr int NCLS  = 10;
constexpr int NHEADS= 8;
constexpr int HDIM  = 32;
constexpr int NTOK  = BATCH*SEQ;      // 16384
constexpr int FFCH  = 8192;           // FFN row chunk

typedef __attribute__((ext_vector_type(8))) short short8;
typedef __attribute__((ext_vector_type(4))) float floatx4;

#define GLOAD_LDS16(g, l) __builtin_amdgcn_global_load_lds( \
    (const __attribute__((address_space(1))) unsigned*)(g), \
    (__attribute__((address_space(3))) unsigned*)(l), 16, 0, 0)

// ---------------- bf16 MFMA GEMM: C[M,N] = A[M,K](bf16) @ W[N,K](bf16)^T + bias ----------------
// M%128==0, N%128==0, K%32==0. m97 structure: 128x128 tile, BK=32, 4 waves (2x2),
// global_load_lds width 16, mfma_f32_16x16x32_bf16, each wave owns a 64x64 sub-tile.
template<bool RELU, bool OUTBF16>
__global__ __launch_bounds__(256)
void gemm_mfma(const __hip_bfloat16* __restrict__ A, int lda,
               const __hip_bfloat16* __restrict__ W,     // [N,K] row-major (= B^T)
               const float* __restrict__ bias,
               void* __restrict__ Cout, int ldc,
               int K)
{
    __shared__ __hip_bfloat16 As[128*32];   // [row][k], 64B/row
    __shared__ __hip_bfloat16 Bs[128*32];
    const int bm = blockIdx.y*128, bn = blockIdx.x*128;
    const int tid  = threadIdx.x;
    const int lane = tid & 63;
    const int w    = tid >> 6;
    const int wm   = (w >> 1)*64, wn = (w & 1)*64;

    floatx4 acc[4][4] = {};

    // staging: wave w stages chunks {2w,2w+1}; chunk c = rows 16c..16c+15 (1024B)
    const int srow = w*32 + (lane >> 2);        // row within tile for chunk 2w
    const int scol = (lane & 3)*8;              // bf16 col
    const __hip_bfloat16* gA0 = A + (size_t)(bm + srow)*lda + scol;
    const __hip_bfloat16* gA1 = A + (size_t)(bm + srow + 16)*lda + scol;
    const __hip_bfloat16* gB0 = W + (size_t)(bn + srow)*K + scol;
    const __hip_bfloat16* gB1 = W + (size_t)(bn + srow + 16)*K + scol;
    __hip_bfloat16* lA0 = As + (w*2    )*512;   // 1024B chunks (wave-uniform)
    __hip_bfloat16* lA1 = As + (w*2 + 1)*512;
    __hip_bfloat16* lB0 = Bs + (w*2    )*512;
    __hip_bfloat16* lB1 = Bs + (w*2 + 1)*512;

    // fragment read indices (short8 units: row*4 + khalf)
    const int arow = wm + (lane & 15);
    const int brow = wn + (lane & 15);
    const int kh   = lane >> 4;                 // 0..3

    for (int k0 = 0; k0 < K; k0 += 32) {
        GLOAD_LDS16(gA0 + k0, lA0);
        GLOAD_LDS16(gA1 + k0, lA1);
        GLOAD_LDS16(gB0 + k0, lB0);
        GLOAD_LDS16(gB1 + k0, lB1);
        __syncthreads();
        short8 af[4], bf[4];
        #pragma unroll
        for (int m = 0; m < 4; m++) af[m] = ((const short8*)As)[(arow + m*16)*4 + kh];
        #pragma unroll
        for (int n = 0; n < 4; n++) bf[n] = ((const short8*)Bs)[(brow + n*16)*4 + kh];
        #pragma unroll
        for (int m = 0; m < 4; m++)
            #pragma unroll
            for (int n = 0; n < 4; n++)
                acc[m][n] = __builtin_amdgcn_mfma_f32_16x16x32_bf16(af[m], bf[n], acc[m][n], 0, 0, 0);
        __syncthreads();
    }

    // epilogue: C/D layout col=lane&15, row=(lane>>4)*4+r
    const int crow0 = bm + wm + (lane >> 4)*4;
    const int ccol0 = bn + wn + (lane & 15);
    #pragma unroll
    for (int n = 0; n < 4; n++) {
        const int col = ccol0 + n*16;
        const float bv = bias[col];
        #pragma unroll
        for (int m = 0; m < 4; m++) {
            #pragma unroll
            for (int r = 0; r < 4; r++) {
                int row = crow0 + m*16 + r;
                float v = acc[m][n][r] + bv;
                if (RELU) v = fmaxf(v, 0.f);
                if (OUTBF16)
                    ((__hip_bfloat16*)Cout)[(size_t)row*ldc + col] = __float2bfloat16(v);
                else
                    ((float*)Cout)[(size_t)row*ldc + col] = v;
            }
        }
    }
}

// ---------------- fp32 -> bf16 convert (n % 4 == 0) ----------------
__global__ void f2b(const float* __restrict__ in, __hip_bfloat16* __restrict__ out, int n)
{
    int i = (blockIdx.x*blockDim.x + threadIdx.x)*4;
    if (i >= n) return;
    float4 v = *(const float4*)(in + i);
    __hip_bfloat16 tmp[4];
    tmp[0] = __float2bfloat16(v.x); tmp[1] = __float2bfloat16(v.y);
    tmp[2] = __float2bfloat16(v.z); tmp[3] = __float2bfloat16(v.w);
    *(ushort4*)(out + i) = *(const ushort4*)tmp;
}

// ---------------- small fp32 GEMM (q rows only): C[M,N]=A@W^T+b ----------------
template<bool RELU>
__global__ void gemm_bias(const float* __restrict__ A, int lda,
                          const float* __restrict__ W,
                          const float* __restrict__ bias,
                          float* __restrict__ Co, int ldc,
                          int M, int N, int K)
{
    __shared__ float Asm[16][65];
    __shared__ float Bsm[16][65];
    const int bm = blockIdx.y*64, bn = blockIdx.x*64;
    const int tx = threadIdx.x, ty = threadIdx.y;
    const int tid = ty*16+tx;
    float acc[4][4] = {};
    for (int k0 = 0; k0 < K; k0 += 16) {
        #pragma unroll
        for (int i = 0; i < 4; i++) {
            int idx = i*256 + tid;
            int r = idx >> 4, kk = idx & 15;
            Asm[kk][r] = (bm+r < M) ? A[(size_t)(bm+r)*lda + k0+kk] : 0.f;
            Bsm[kk][r] = (bn+r < N) ? W[(size_t)(bn+r)*K  + k0+kk] : 0.f;
        }
        __syncthreads();
        #pragma unroll
        for (int k = 0; k < 16; k++) {
            float a[4], b[4];
            #pragma unroll
            for (int i = 0; i < 4; i++) a[i] = Asm[k][ty*4+i];
            #pragma unroll
            for (int j = 0; j < 4; j++) b[j] = Bsm[k][tx*4+j];
            #pragma unroll
            for (int i = 0; i < 4; i++)
                #pragma unroll
                for (int j = 0; j < 4; j++)
                    acc[i][j] += a[i]*b[j];
        }
        __syncthreads();
    }
    #pragma unroll
    for (int i = 0; i < 4; i++) {
        int m = bm + ty*4 + i; if (m >= M) continue;
        #pragma unroll
        for (int j = 0; j < 4; j++) {
            int n = bn + tx*4 + j; if (n >= N) continue;
            float v = acc[i][j] + bias[n];
            if (RELU) v = fmaxf(v, 0.f);
            Co[(size_t)m*ldc + n] = v;
        }
    }
}

// ---------------- embed + scale + pos-enc; writes fp32 + bf16 mirrors ----------------
__global__ void embed_kernel(const float* __restrict__ src,
                             const float* __restrict__ emb_W,
                             const float* __restrict__ emb_b,
                             float* __restrict__ x,
                             __hip_bfloat16* __restrict__ xb)
{
    int row = blockIdx.x;
    int e = threadIdx.x;
    int s = row % SEQ;
    const float* sr = src + (size_t)row*DIN;
    float acc = emb_b[e];
    #pragma unroll
    for (int d = 0; d < DIN; d++) acc += sr[d]*emb_W[e*DIN + d];
    acc *= 16.0f;                    // sqrt(EMB)
    int i2 = e & ~1;
    float div = expf(-(float)i2 * (9.210340371976184f / (float)EMB));
    float ang = (float)s * div;
    float pe = (e & 1) ? cosf(ang) : sinf(ang);
    float v = acc + pe;
    x [(size_t)row*EMB + e] = v;
    xb[(size_t)row*EMB + e] = __float2bfloat16(v);
}

__global__ void pack_last(const float* __restrict__ x, float* __restrict__ xl)
{
    int b = blockIdx.x, e = threadIdx.x;
    xl[b*EMB + e] = x[((size_t)b*SEQ + SEQ-1)*EMB + e];
}

// ---------------- last-row attention on bf16 kv ----------------
__global__ void attn_last(const float* __restrict__ ql,        // [B,256] fp32
                          __hip_bfloat16* __restrict__ kv,     // [B*S,512] k|v
                          float* __restrict__ amL)             // [B,SEQ]
{
    int b = blockIdx.x;
    int t = threadIdx.x;             // 0..511
    __shared__ float sc[NHEADS][SEQ];
    __hip_bfloat16* kvb = kv + (size_t)b*SEQ*512;

    #pragma unroll
    for (int h = 0; h < NHEADS; h++) {
        const float* qh = ql + b*EMB + h*HDIM;
        const __hip_bfloat16* khp = kvb + (size_t)t*512 + h*HDIM;
        float s = 0.f;
        #pragma unroll
        for (int d = 0; d < HDIM; d++) s += qh[d]*__bfloat162float(khp[d]);
        s *= 0.17677669529663687f;
        if (t == SEQ-1) s += -1e9f;
        sc[h][t] = s;
    }
    __syncthreads();

    {
        int wv = t >> 6, lane = t & 63;
        float pv[SEQ/64];
        float m = -1e30f;
        #pragma unroll
        for (int j = 0; j < SEQ/64; j++) { pv[j] = sc[wv][lane + j*64]; m = fmaxf(m, pv[j]); }
        #pragma unroll
        for (int o = 32; o; o >>= 1) m = fmaxf(m, __shfl_xor(m, o));
        float ssum = 0.f;
        #pragma unroll
        for (int j = 0; j < SEQ/64; j++) { pv[j] = expf(pv[j] - m); ssum += pv[j]; }
        #pragma unroll
        for (int o = 32; o; o >>= 1) ssum += __shfl_xor(ssum, o);
        float inv = 1.f/ssum;
        #pragma unroll
        for (int j = 0; j < SEQ/64; j++) sc[wv][lane + j*64] = pv[j]*inv;
    }
    __syncthreads();

    {
        float a = 0.f;
        #pragma unroll
        for (int h = 0; h < NHEADS; h++) a += sc[h][t];
        amL[b*SEQ + t] = a * 0.125f;
    }

    if (t < EMB) {
        int h = t >> 5;
        float o = 0.f;
        for (int k = 0; k < SEQ; k++) o += sc[h][k] * __bfloat162float(kvb[(size_t)k*512 + 256 + t]);
        kvb[(size_t)(SEQ-1)*512 + 256 + t] = __float2bfloat16(o);
    }
}

// ---------------- residual + layernorm; writes fp32 + bf16 mirrors ----------------
__global__ void resln(float* __restrict__ x, __hip_bfloat16* __restrict__ xb,
                      const float* __restrict__ t,
                      const float* __restrict__ g, const float* __restrict__ bb)
{
    int row = blockIdx.x;
    int e = threadIdx.x;
    __shared__ float red1[4], red2[4];
    float v = x[(size_t)row*EMB + e] + t[(size_t)row*EMB + e];
    float s = v;
    #pragma unroll
    for (int o = 32; o; o >>= 1) s += __shfl_xor(s, o);
    if ((e & 63) == 0) red1[e >> 6] = s;
    __syncthreads();
    float mean = (red1[0]+red1[1]+red1[2]+red1[3]) * (1.f/EMB);
    float d = v - mean;
    float s2 = d*d;
    #pragma unroll
    for (int o = 32; o; o >>= 1) s2 += __shfl_xor(s2, o);
    if ((e & 63) == 0) red2[e >> 6] = s2;
    __syncthreads();
    float var = (red2[0]+red2[1]+red2[2]+red2[3]) * (1.f/EMB);
    float r = d * (1.f/sqrtf(var + 1e-5f)) * g[e] + bb[e];
    x [(size_t)row*EMB + e] = r;
    xb[(size_t)row*EMB + e] = __float2bfloat16(r);
}

// ---------------- write full attns output [L,B,S,S] ----------------
__global__ void write_attns(float* __restrict__ attns, const float* __restrict__ am_all)
{
    constexpr int PER_ROW = SEQ/4;
    size_t tid = (size_t)blockIdx.x*blockDim.x + threadIdx.x;
    size_t row = tid / PER_ROW;
    int c4 = (int)(tid % PER_ROW);
    int q = (int)(row % SEQ);
    float4 v = make_float4(0.f,0.f,0.f,0.f);
    if (q == SEQ-1) {
        size_t lb = row / SEQ;
        const float* amr = am_all + lb*SEQ + c4*4;
        v = make_float4(amr[0], amr[1], amr[2], amr[3]);
    } else if ((q >> 2) == c4) {
        ((float*)&v)[q & 3] = 1.f;
    }
    ((float4*)attns)[tid] = v;
}

// ---------------- partial relu-sum over sequence chunks ----------------
__global__ void reduce_relu_part(const float* __restrict__ x, float* __restrict__ rp)
{
    int b = blockIdx.x, ch = blockIdx.y, e = threadIdx.x;
    const float* xb = x + ((size_t)b*SEQ + ch*(SEQ/8))*EMB;
    float s = 0.f;
    for (int i = 0; i < SEQ/8; i++) s += fmaxf(xb[(size_t)i*EMB + e], 0.f);
    rp[(b*8 + ch)*EMB + e] = s;
}

// ---------------- decode + log_softmax ----------------
__global__ void decode_out(const float* __restrict__ rp, const float* __restrict__ dec_W,
                           float* __restrict__ out)
{
    __shared__ float logits[BATCH][NCLS];
    int tid = threadIdx.x;
    if (tid < BATCH*NCLS) {
        int b = tid / NCLS, c = tid % NCLS;
        float acc = 0.f;
        for (int ch = 0; ch < 8; ch++)
            for (int e = 0; e < EMB; e++) acc += rp[(b*8+ch)*EMB + e]*dec_W[c*EMB + e];
        logits[b][c] = acc * (1.f/(float)SEQ);
    }
    __syncthreads();
    if (tid < BATCH) {
        float m = -1e30f;
        #pragma unroll
        for (int c = 0; c < NCLS; c++) m = fmaxf(m, logits[tid][c]);
        float s = 0.f;
        #pragma unroll
        for (int c = 0; c < NCLS; c++) s += expf(logits[tid][c] - m);
        float ls = logf(s);
        #pragma unroll
        for (int c = 0; c < NCLS; c++) out[tid*NCLS + c] = logits[tid][c] - m - ls;
    }
}

} // namespace

extern "C" void kernel_launch(void* const* d_in, const int* in_sizes, int n_in,
                              void* d_out, int out_size, void* d_ws, size_t ws_size,
                              hipStream_t stream)
{
    const float* src   = (const float*)d_in[0];
    const float* emb_W = (const float*)d_in[1];
    const float* emb_b = (const float*)d_in[2];
    const float* Wqkv  = (const float*)d_in[3];
    const float* bqkv  = (const float*)d_in[4];
    const float* Wo    = (const float*)d_in[5];
    const float* bo    = (const float*)d_in[6];
    const float* ln1_g = (const float*)d_in[7];
    const float* ln1_b = (const float*)d_in[8];
    const float* ln2_g = (const float*)d_in[9];
    const float* ln2_b = (const float*)d_in[10];
    const float* W1    = (const float*)d_in[11];
    const float* b1    = (const float*)d_in[12];
    const float* W2    = (const float*)d_in[13];
    const float* b2    = (const float*)d_in[14];
    const float* dec_W = (const float*)d_in[15];

    float* out   = (float*)d_out;               // [32,10]
    float* attns = out + BATCH*NCLS;            // [4,32,512,512]

    // workspace layout (bytes): total ~82 MB
    char* ws = (char*)d_ws;
    float*          xbuf = (float*)ws;                              ws += (size_t)NTOK*EMB*4;     // 16.78 MB
    __hip_bfloat16* xb16 = (__hip_bfloat16*)ws;                     ws += (size_t)NTOK*EMB*2;     //  8.39 MB
    __hip_bfloat16* kv   = (__hip_bfloat16*)ws;                     ws += (size_t)NTOK*512*2;     // 16.78 MB
    float*          tbuf = (float*)ws;                              ws += (size_t)NTOK*EMB*4;     // 16.78 MB
    __hip_bfloat16* hbuf = (__hip_bfloat16*)ws;                     ws += (size_t)FFCH*FF*2;      // 16.78 MB
    __hip_bfloat16* wq16 = (__hip_bfloat16*)ws;                     ws += (size_t)NLAYER*3*EMB*EMB*2;
    __hip_bfloat16* wo16 = (__hip_bfloat16*)ws;                     ws += (size_t)NLAYER*EMB*EMB*2;
    __hip_bfloat16* w116 = (__hip_bfloat16*)ws;                     ws += (size_t)NLAYER*FF*EMB*2;
    __hip_bfloat16* w216 = (__hip_bfloat16*)ws;                     ws += (size_t)NLAYER*EMB*FF*2;
    float*          xl   = (float*)ws;                              ws += BATCH*EMB*4;
    float*          ql   = (float*)ws;                              ws += BATCH*EMB*4;
    float*          amall= (float*)ws;                              ws += (size_t)NLAYER*BATCH*SEQ*4;
    float*          rpart= (float*)ws;                              ws += BATCH*8*EMB*4;

    // weight conversion fp32 -> bf16
    f2b<<<NLAYER*3*EMB*EMB/4/256, 256, 0, stream>>>(Wqkv, wq16, NLAYER*3*EMB*EMB);
    f2b<<<NLAYER*EMB*EMB/4/256,   256, 0, stream>>>(Wo,   wo16, NLAYER*EMB*EMB);
    f2b<<<NLAYER*FF*EMB/4/256,    256, 0, stream>>>(W1,   w116, NLAYER*FF*EMB);
    f2b<<<NLAYER*EMB*FF/4/256,    256, 0, stream>>>(W2,   w216, NLAYER*EMB*FF);

    embed_kernel<<<NTOK, EMB, 0, stream>>>(src, emb_W, emb_b, xbuf, xb16);

    dim3 gblk(16,16);
    for (int l = 0; l < NLAYER; l++) {
        // q for last tokens only (fp32, tiny)
        pack_last<<<BATCH, EMB, 0, stream>>>(xbuf, xl);
        gemm_bias<false><<<dim3(EMB/64, 1), gblk, 0, stream>>>(
            xl, EMB, Wqkv + (size_t)l*3*EMB*EMB, bqkv + (size_t)l*3*EMB, ql, EMB, BATCH, EMB, EMB);

        // k,v for all tokens (bf16 MFMA): W rows [E..3E)
        gemm_mfma<false, true><<<dim3(512/128, NTOK/128), 256, 0, stream>>>(
            xb16, EMB, wq16 + (size_t)l*3*EMB*EMB + (size_t)EMB*EMB,
            bqkv + (size_t)l*3*EMB + EMB, kv, 512, EMB);

        attn_last<<<BATCH, SEQ, 0, stream>>>(ql, kv, amall + (size_t)l*BATCH*SEQ);

        // o @ Wo^T + bo  (o == v with last row replaced), fp32 out
        gemm_mfma<false, false><<<dim3(EMB/128, NTOK/128), 256, 0, stream>>>(
            kv + 256, 512, wo16 + (size_t)l*EMB*EMB, bo + (size_t)l*EMB, tbuf, EMB, EMB);

        resln<<<NTOK, EMB, 0, stream>>>(xbuf, xb16, tbuf, ln1_g + l*EMB, ln1_b + l*EMB);

        for (int ch = 0; ch < NTOK; ch += FFCH) {
            gemm_mfma<true, true><<<dim3(FF/128, FFCH/128), 256, 0, stream>>>(
                xb16 + (size_t)ch*EMB, EMB, w116 + (size_t)l*FF*EMB, b1 + (size_t)l*FF,
                hbuf, FF, EMB);
            gemm_mfma<false, false><<<dim3(EMB/128, FFCH/128), 256, 0, stream>>>(
                hbuf, FF, w216 + (size_t)l*EMB*FF, b2 + (size_t)l*EMB,
                tbuf + (size_t)ch*EMB, EMB, FF);
        }
        resln<<<NTOK, EMB, 0, stream>>>(xbuf, xb16, tbuf, ln2_g + l*EMB, ln2_b + l*EMB);
    }

    {
        size_t total_f4 = (size_t)NLAYER*BATCH*SEQ*(SEQ/4);
        int blocks = (int)((total_f4 + 255)/256);
        write_attns<<<blocks, 256, 0, stream>>>(attns, amall);
    }

    reduce_relu_part<<<dim3(BATCH, 8), EMB, 0, stream>>>(xbuf, rpart);
    decode_out<<<1, 384, 0, stream>>>(rpart, dec_W, out);
}

// Round 5
// 967.267 us; speedup vs baseline: 4.9662x; 1.1116x over previous
//
#include <hip/hip_runtime.h>
#include <hip/hip_bf16.h>
#include <math.h>

namespace {

constexpr int BATCH = 32;
constexpr int SEQ   = 512;
constexpr int DIN   = 9;
constexpr int EMB   = 256;
constexpr int FF    = 1024;
constexpr int NLAYER= 4;
constexpr int NCLS  = 10;
constexpr int NHEADS= 8;
constexpr int HDIM  = 32;
constexpr int NTOK  = BATCH*SEQ;      // 16384

typedef __attribute__((ext_vector_type(8))) short short8;
typedef __attribute__((ext_vector_type(4))) float floatx4;

#define GLOAD_LDS16(g, l) __builtin_amdgcn_global_load_lds( \
    (const __attribute__((address_space(1))) unsigned*)(g), \
    (__attribute__((address_space(3))) unsigned*)(l), 16, 0, 0)

// ---------------- bf16 MFMA GEMM: C[M,N] = A[M,K](bf16) @ W[N,K](bf16)^T + bias ----------------
// M%128==0, N%128==0, K%32==0. m97 structure: 128x128 tile, BK=32, 4 waves (2x2),
// global_load_lds width 16, mfma_f32_16x16x32_bf16, each wave owns a 64x64 sub-tile.
template<bool RELU, bool OUTBF16>
__global__ __launch_bounds__(256)
void gemm_mfma(const __hip_bfloat16* __restrict__ A, int lda,
               const __hip_bfloat16* __restrict__ W,     // [N,K] row-major (= B^T)
               const float* __restrict__ bias,
               void* __restrict__ Cout, int ldc,
               int K)
{
    __shared__ __hip_bfloat16 As[128*32];   // [row][k], 64B/row
    __shared__ __hip_bfloat16 Bs[128*32];
    const int bm = blockIdx.y*128, bn = blockIdx.x*128;
    const int tid  = threadIdx.x;
    const int lane = tid & 63;
    const int w    = tid >> 6;
    const int wm   = (w >> 1)*64, wn = (w & 1)*64;

    floatx4 acc[4][4] = {};

    const int srow = w*32 + (lane >> 2);        // row within tile for chunk 2w
    const int scol = (lane & 3)*8;              // bf16 col
    const __hip_bfloat16* gA0 = A + (size_t)(bm + srow)*lda + scol;
    const __hip_bfloat16* gA1 = A + (size_t)(bm + srow + 16)*lda + scol;
    const __hip_bfloat16* gB0 = W + (size_t)(bn + srow)*K + scol;
    const __hip_bfloat16* gB1 = W + (size_t)(bn + srow + 16)*K + scol;
    __hip_bfloat16* lA0 = As + (w*2    )*512;
    __hip_bfloat16* lA1 = As + (w*2 + 1)*512;
    __hip_bfloat16* lB0 = Bs + (w*2    )*512;
    __hip_bfloat16* lB1 = Bs + (w*2 + 1)*512;

    const int arow = wm + (lane & 15);
    const int brow = wn + (lane & 15);
    const int kh   = lane >> 4;                 // 0..3

    for (int k0 = 0; k0 < K; k0 += 32) {
        GLOAD_LDS16(gA0 + k0, lA0);
        GLOAD_LDS16(gA1 + k0, lA1);
        GLOAD_LDS16(gB0 + k0, lB0);
        GLOAD_LDS16(gB1 + k0, lB1);
        __syncthreads();
        short8 af[4], bf[4];
        #pragma unroll
        for (int m = 0; m < 4; m++) af[m] = ((const short8*)As)[(arow + m*16)*4 + kh];
        #pragma unroll
        for (int n = 0; n < 4; n++) bf[n] = ((const short8*)Bs)[(brow + n*16)*4 + kh];
        #pragma unroll
        for (int m = 0; m < 4; m++)
            #pragma unroll
            for (int n = 0; n < 4; n++)
                acc[m][n] = __builtin_amdgcn_mfma_f32_16x16x32_bf16(af[m], bf[n], acc[m][n], 0, 0, 0);
        __syncthreads();
    }

    const int crow0 = bm + wm + (lane >> 4)*4;
    const int ccol0 = bn + wn + (lane & 15);
    #pragma unroll
    for (int n = 0; n < 4; n++) {
        const int col = ccol0 + n*16;
        const float bv = bias[col];
        #pragma unroll
        for (int m = 0; m < 4; m++) {
            #pragma unroll
            for (int r = 0; r < 4; r++) {
                int row = crow0 + m*16 + r;
                float v = acc[m][n][r] + bv;
                if (RELU) v = fmaxf(v, 0.f);
                if (OUTBF16)
                    ((__hip_bfloat16*)Cout)[(size_t)row*ldc + col] = __float2bfloat16(v);
                else
                    ((float*)Cout)[(size_t)row*ldc + col] = v;
            }
        }
    }
}

// ---------------- fp32 -> bf16 convert (n % 4 == 0) ----------------
__global__ void f2b(const float* __restrict__ in, __hip_bfloat16* __restrict__ out, int n)
{
    int i = (blockIdx.x*blockDim.x + threadIdx.x)*4;
    if (i >= n) return;
    float4 v = *(const float4*)(in + i);
    __hip_bfloat16 tmp[4];
    tmp[0] = __float2bfloat16(v.x); tmp[1] = __float2bfloat16(v.y);
    tmp[2] = __float2bfloat16(v.z); tmp[3] = __float2bfloat16(v.w);
    *(ushort4*)(out + i) = *(const ushort4*)tmp;
}

// ---------------- embed + scale + pos-enc; writes fp32 + bf16 mirrors ----------------
__global__ void embed_kernel(const float* __restrict__ src,
                             const float* __restrict__ emb_W,
                             const float* __restrict__ emb_b,
                             float* __restrict__ x,
                             __hip_bfloat16* __restrict__ xb)
{
    int row = blockIdx.x;
    int e = threadIdx.x;
    int s = row % SEQ;
    const float* sr = src + (size_t)row*DIN;
    float acc = emb_b[e];
    #pragma unroll
    for (int d = 0; d < DIN; d++) acc += sr[d]*emb_W[e*DIN + d];
    acc *= 16.0f;                    // sqrt(EMB)
    int i2 = e & ~1;
    float div = expf(-(float)i2 * (9.210340371976184f / (float)EMB));
    float ang = (float)s * div;
    float pe = (e & 1) ? cosf(ang) : sinf(ang);
    float v = acc + pe;
    x [(size_t)row*EMB + e] = v;
    xb[(size_t)row*EMB + e] = __float2bfloat16(v);
}

// ---------------- fused last-row attention: q-GEMV + scores + softmax + o + head-avg ----------------
__global__ __launch_bounds__(512)
void attn_last_fused(const float* __restrict__ x,          // [NTOK, EMB] fp32
                     const float* __restrict__ Wq,         // [EMB, EMB] (q rows of Wqkv[l])
                     const float* __restrict__ bq,
                     __hip_bfloat16* __restrict__ kv,      // [B*S,512] k|v
                     float* __restrict__ amL)              // [B,SEQ]
{
    int b = blockIdx.x;
    int t = threadIdx.x;             // 0..511
    __shared__ float xlast[EMB];
    __shared__ float q[EMB];
    __shared__ float sc[NHEADS][SEQ];
    __shared__ float opart[2][EMB];
    __hip_bfloat16* kvb = kv + (size_t)b*SEQ*512;

    if (t < EMB) xlast[t] = x[((size_t)b*SEQ + SEQ-1)*EMB + t];
    __syncthreads();
    if (t < EMB) {
        const float* wr = Wq + (size_t)t*EMB;
        float acc = bq[t];
        for (int k2 = 0; k2 < EMB; k2 += 4) {
            float4 w4 = *(const float4*)(wr + k2);
            acc += xlast[k2]*w4.x + xlast[k2+1]*w4.y + xlast[k2+2]*w4.z + xlast[k2+3]*w4.w;
        }
        q[t] = acc;
    }
    __syncthreads();

    // scores: thread t handles key-row t for all 8 heads (vectorized bf16 loads)
    {
        const __hip_bfloat16* krow = kvb + (size_t)t*512;
        #pragma unroll
        for (int h = 0; h < NHEADS; h++) {
            float s = 0.f;
            #pragma unroll
            for (int vv = 0; vv < 4; vv++) {
                short8 kk = *(const short8*)(krow + h*32 + vv*8);
                #pragma unroll
                for (int j = 0; j < 8; j++) {
                    __hip_bfloat16 hb = ((const __hip_bfloat16*)&kk)[j];
                    s += q[h*32 + vv*8 + j] * __bfloat162float(hb);
                }
            }
            s *= 0.17677669529663687f;
            if (t == SEQ-1) s += -1e9f;
            sc[h][t] = s;
        }
    }
    __syncthreads();

    // per-head softmax: wave w handles head w
    {
        int wv = t >> 6, lane = t & 63;
        float pv[SEQ/64];
        float m = -1e30f;
        #pragma unroll
        for (int j = 0; j < SEQ/64; j++) { pv[j] = sc[wv][lane + j*64]; m = fmaxf(m, pv[j]); }
        #pragma unroll
        for (int o = 32; o; o >>= 1) m = fmaxf(m, __shfl_xor(m, o));
        float ssum = 0.f;
        #pragma unroll
        for (int j = 0; j < SEQ/64; j++) { pv[j] = expf(pv[j] - m); ssum += pv[j]; }
        #pragma unroll
        for (int o = 32; o; o >>= 1) ssum += __shfl_xor(ssum, o);
        float inv = 1.f/ssum;
        #pragma unroll
        for (int j = 0; j < SEQ/64; j++) sc[wv][lane + j*64] = pv[j]*inv;
    }
    __syncthreads();

    // head-averaged attention row
    {
        float a = 0.f;
        #pragma unroll
        for (int h = 0; h < NHEADS; h++) a += sc[h][t];
        amL[b*SEQ + t] = a * 0.125f;
    }

    // o_last: 512 threads, e = t&255, k-half = t>>8
    {
        int e = t & (EMB-1), hf = t >> 8;
        int h = e >> 5;
        float o = 0.f;
        const __hip_bfloat16* vcol = kvb + 256 + e;
        for (int k = hf*256; k < hf*256 + 256; k++)
            o += sc[h][k] * __bfloat162float(vcol[(size_t)k*512]);
        opart[hf][e] = o;
    }
    __syncthreads();
    if (t < EMB)
        kvb[(size_t)(SEQ-1)*512 + 256 + t] = __float2bfloat16(opart[0][t] + opart[1][t]);
}

// ---------------- residual + layernorm; writes fp32 + bf16 mirrors ----------------
__global__ void resln(float* __restrict__ x, __hip_bfloat16* __restrict__ xb,
                      const float* __restrict__ t,
                      const float* __restrict__ g, const float* __restrict__ bb)
{
    int row = blockIdx.x;
    int e = threadIdx.x;
    __shared__ float red1[4], red2[4];
    float v = x[(size_t)row*EMB + e] + t[(size_t)row*EMB + e];
    float s = v;
    #pragma unroll
    for (int o = 32; o; o >>= 1) s += __shfl_xor(s, o);
    if ((e & 63) == 0) red1[e >> 6] = s;
    __syncthreads();
    float mean = (red1[0]+red1[1]+red1[2]+red1[3]) * (1.f/EMB);
    float d = v - mean;
    float s2 = d*d;
    #pragma unroll
    for (int o = 32; o; o >>= 1) s2 += __shfl_xor(s2, o);
    if ((e & 63) == 0) red2[e >> 6] = s2;
    __syncthreads();
    float var = (red2[0]+red2[1]+red2[2]+red2[3]) * (1.f/EMB);
    float r = d * (1.f/sqrtf(var + 1e-5f)) * g[e] + bb[e];
    x [(size_t)row*EMB + e] = r;
    xb[(size_t)row*EMB + e] = __float2bfloat16(r);
}

// ---------------- write full attns output [L,B,S,S] ----------------
__global__ void write_attns(float* __restrict__ attns, const float* __restrict__ am_all)
{
    constexpr int PER_ROW = SEQ/4;
    size_t tid = (size_t)blockIdx.x*blockDim.x + threadIdx.x;
    size_t row = tid / PER_ROW;
    int c4 = (int)(tid % PER_ROW);
    int q = (int)(row % SEQ);
    float4 v = make_float4(0.f,0.f,0.f,0.f);
    if (q == SEQ-1) {
        size_t lb = row / SEQ;
        const float* amr = am_all + lb*SEQ + c4*4;
        v = make_float4(amr[0], amr[1], amr[2], amr[3]);
    } else if ((q >> 2) == c4) {
        ((float*)&v)[q & 3] = 1.f;
    }
    ((float4*)attns)[tid] = v;
}

// ---------------- partial relu-sum over sequence chunks ----------------
__global__ void reduce_relu_part(const float* __restrict__ x, float* __restrict__ rp)
{
    int b = blockIdx.x, ch = blockIdx.y, e = threadIdx.x;
    const float* xb = x + ((size_t)b*SEQ + ch*(SEQ/8))*EMB;
    float s = 0.f;
    for (int i = 0; i < SEQ/8; i++) s += fmaxf(xb[(size_t)i*EMB + e], 0.f);
    rp[(b*8 + ch)*EMB + e] = s;
}

// ---------------- parallel decode + log_softmax: one block per batch row ----------------
__global__ __launch_bounds__(256)
void decode_out2(const float* __restrict__ rp, const float* __restrict__ dec_W,
                 float* __restrict__ out)
{
    int b = blockIdx.x, t = threadIdx.x;    // 256 threads
    float r = 0.f;
    #pragma unroll
    for (int ch = 0; ch < 8; ch++) r += rp[(b*8 + ch)*EMB + t];
    float part[NCLS];
    #pragma unroll
    for (int c = 0; c < NCLS; c++) part[c] = r * dec_W[c*EMB + t];
    #pragma unroll
    for (int o = 32; o; o >>= 1)
        #pragma unroll
        for (int c = 0; c < NCLS; c++) part[c] += __shfl_xor(part[c], o);
    __shared__ float red[4][NCLS];
    int wv = t >> 6, lane = t & 63;
    if (lane == 0)
        #pragma unroll
        for (int c = 0; c < NCLS; c++) red[wv][c] = part[c];
    __syncthreads();
    if (t == 0) {
        float lg[NCLS];
        float m = -1e30f;
        #pragma unroll
        for (int c = 0; c < NCLS; c++) {
            lg[c] = (red[0][c]+red[1][c]+red[2][c]+red[3][c]) * (1.f/(float)SEQ);
            m = fmaxf(m, lg[c]);
        }
        float s = 0.f;
        #pragma unroll
        for (int c = 0; c < NCLS; c++) s += expf(lg[c] - m);
        float ls = logf(s);
        #pragma unroll
        for (int c = 0; c < NCLS; c++) out[b*NCLS + c] = lg[c] - m - ls;
    }
}

} // namespace

extern "C" void kernel_launch(void* const* d_in, const int* in_sizes, int n_in,
                              void* d_out, int out_size, void* d_ws, size_t ws_size,
                              hipStream_t stream)
{
    const float* src   = (const float*)d_in[0];
    const float* emb_W = (const float*)d_in[1];
    const float* emb_b = (const float*)d_in[2];
    const float* Wqkv  = (const float*)d_in[3];
    const float* bqkv  = (const float*)d_in[4];
    const float* Wo    = (const float*)d_in[5];
    const float* bo    = (const float*)d_in[6];
    const float* ln1_g = (const float*)d_in[7];
    const float* ln1_b = (const float*)d_in[8];
    const float* ln2_g = (const float*)d_in[9];
    const float* ln2_b = (const float*)d_in[10];
    const float* W1    = (const float*)d_in[11];
    const float* b1    = (const float*)d_in[12];
    const float* W2    = (const float*)d_in[13];
    const float* b2    = (const float*)d_in[14];
    const float* dec_W = (const float*)d_in[15];

    float* out   = (float*)d_out;               // [32,10]
    float* attns = out + BATCH*NCLS;            // [4,32,512,512]

    // workspace layout (~82 MB). kv and the FFN hidden buffer alias the same
    // region (union): kv = [NTOK,512] bf16 lives in the first 16.78 MB of the
    // [NTOK,FF] bf16 hidden buffer — they are never live simultaneously.
    char* ws = (char*)d_ws;
    float*          xbuf = (float*)ws;              ws += (size_t)NTOK*EMB*4;     // 16.78 MB
    __hip_bfloat16* xb16 = (__hip_bfloat16*)ws;     ws += (size_t)NTOK*EMB*2;     //  8.39 MB
    __hip_bfloat16* kvh  = (__hip_bfloat16*)ws;     ws += (size_t)NTOK*FF*2;      // 33.55 MB (kv | hidden)
    float*          tbuf = (float*)ws;              ws += (size_t)NTOK*EMB*4;     // 16.78 MB
    __hip_bfloat16* wq16 = (__hip_bfloat16*)ws;     ws += (size_t)NLAYER*3*EMB*EMB*2;
    __hip_bfloat16* wo16 = (__hip_bfloat16*)ws;     ws += (size_t)NLAYER*EMB*EMB*2;
    __hip_bfloat16* w116 = (__hip_bfloat16*)ws;     ws += (size_t)NLAYER*FF*EMB*2;
    __hip_bfloat16* w216 = (__hip_bfloat16*)ws;     ws += (size_t)NLAYER*EMB*FF*2;
    float*          amall= (float*)ws;              ws += (size_t)NLAYER*BATCH*SEQ*4;
    float*          rpart= (float*)ws;              ws += BATCH*8*EMB*4;

    __hip_bfloat16* kv   = kvh;                     // [NTOK, 512]
    __hip_bfloat16* hbuf = kvh;                     // [NTOK, FF]

    // weight conversion fp32 -> bf16
    f2b<<<NLAYER*3*EMB*EMB/4/256, 256, 0, stream>>>(Wqkv, wq16, NLAYER*3*EMB*EMB);
    f2b<<<NLAYER*EMB*EMB/4/256,   256, 0, stream>>>(Wo,   wo16, NLAYER*EMB*EMB);
    f2b<<<NLAYER*FF*EMB/4/256,    256, 0, stream>>>(W1,   w116, NLAYER*FF*EMB);
    f2b<<<NLAYER*EMB*FF/4/256,    256, 0, stream>>>(W2,   w216, NLAYER*EMB*FF);

    embed_kernel<<<NTOK, EMB, 0, stream>>>(src, emb_W, emb_b, xbuf, xb16);

    for (int l = 0; l < NLAYER; l++) {
        // k,v for all tokens (bf16 MFMA): W rows [E..3E)
        gemm_mfma<false, true><<<dim3(512/128, NTOK/128), 256, 0, stream>>>(
            xb16, EMB, wq16 + (size_t)l*3*EMB*EMB + (size_t)EMB*EMB,
            bqkv + (size_t)l*3*EMB + EMB, kv, 512, EMB);

        // fused: q GEMV (fp32) + scores + softmax + head-avg + o_last
        attn_last_fused<<<BATCH, 512, 0, stream>>>(
            xbuf, Wqkv + (size_t)l*3*EMB*EMB, bqkv + (size_t)l*3*EMB,
            kv, amall + (size_t)l*BATCH*SEQ);

        // o @ Wo^T + bo  (o == v with last row replaced), fp32 out
        gemm_mfma<false, false><<<dim3(EMB/128, NTOK/128), 256, 0, stream>>>(
            kv + 256, 512, wo16 + (size_t)l*EMB*EMB, bo + (size_t)l*EMB, tbuf, EMB, EMB);

        resln<<<NTOK, EMB, 0, stream>>>(xbuf, xb16, tbuf, ln1_g + l*EMB, ln1_b + l*EMB);

        // FFN, full 16384 rows per launch (kv region now dead -> reuse as hidden)
        gemm_mfma<true, true><<<dim3(FF/128, NTOK/128), 256, 0, stream>>>(
            xb16, EMB, w116 + (size_t)l*FF*EMB, b1 + (size_t)l*FF, hbuf, FF, EMB);
        gemm_mfma<false, false><<<dim3(EMB/128, NTOK/128), 256, 0, stream>>>(
            hbuf, FF, w216 + (size_t)l*EMB*FF, b2 + (size_t)l*EMB, tbuf, EMB, FF);

        resln<<<NTOK, EMB, 0, stream>>>(xbuf, xb16, tbuf, ln2_g + l*EMB, ln2_b + l*EMB);
    }

    {
        size_t total_f4 = (size_t)NLAYER*BATCH*SEQ*(SEQ/4);
        int blocks = (int)((total_f4 + 255)/256);
        write_attns<<<blocks, 256, 0, stream>>>(attns, amall);
    }

    reduce_relu_part<<<dim3(BATCH, 8), EMB, 0, stream>>>(xbuf, rpart);
    decode_out2<<<BATCH, 256, 0, stream>>>(rpart, dec_W, out);
}

// Round 6
// 678.963 us; speedup vs baseline: 7.0750x; 1.4246x over previous
//
#include <hip/hip_runtime.h>
#include <hip/hip_bf16.h>
#include <math.h>

namespace {

constexpr int BATCH = 32;
constexpr int SEQ   = 512;
constexpr int DIN   = 9;
constexpr int EMB   = 256;
constexpr int FF    = 1024;
constexpr int NLAYER= 4;
constexpr int NCLS  = 10;
constexpr int NHEADS= 8;
constexpr int HDIM  = 32;
constexpr int NTOK  = BATCH*SEQ;      // 16384

typedef __attribute__((ext_vector_type(8))) short short8;
typedef __attribute__((ext_vector_type(4))) float floatx4;

#define GLOAD_LDS16(g, l) __builtin_amdgcn_global_load_lds( \
    (const __attribute__((address_space(1))) unsigned*)(g), \
    (__attribute__((address_space(3))) unsigned*)(l), 16, 0, 0)

// ---------------- bf16 MFMA GEMM: C[M,N] = A[M,K](bf16) @ W[N,K](bf16)^T + bias ----------------
template<bool RELU, bool OUTBF16>
__global__ __launch_bounds__(256)
void gemm_mfma(const __hip_bfloat16* __restrict__ A, int lda,
               const __hip_bfloat16* __restrict__ W,     // [N,K] row-major (= B^T)
               const float* __restrict__ bias,
               void* __restrict__ Cout, int ldc,
               int K)
{
    __shared__ __hip_bfloat16 As[128*32];   // [row][k], 64B/row
    __shared__ __hip_bfloat16 Bs[128*32];
    const int bm = blockIdx.y*128, bn = blockIdx.x*128;
    const int tid  = threadIdx.x;
    const int lane = tid & 63;
    const int w    = tid >> 6;
    const int wm   = (w >> 1)*64, wn = (w & 1)*64;

    floatx4 acc[4][4] = {};

    const int srow = w*32 + (lane >> 2);
    const int scol = (lane & 3)*8;
    const __hip_bfloat16* gA0 = A + (size_t)(bm + srow)*lda + scol;
    const __hip_bfloat16* gA1 = A + (size_t)(bm + srow + 16)*lda + scol;
    const __hip_bfloat16* gB0 = W + (size_t)(bn + srow)*K + scol;
    const __hip_bfloat16* gB1 = W + (size_t)(bn + srow + 16)*K + scol;
    __hip_bfloat16* lA0 = As + (w*2    )*512;
    __hip_bfloat16* lA1 = As + (w*2 + 1)*512;
    __hip_bfloat16* lB0 = Bs + (w*2    )*512;
    __hip_bfloat16* lB1 = Bs + (w*2 + 1)*512;

    const int arow = wm + (lane & 15);
    const int brow = wn + (lane & 15);
    const int kh   = lane >> 4;

    for (int k0 = 0; k0 < K; k0 += 32) {
        GLOAD_LDS16(gA0 + k0, lA0);
        GLOAD_LDS16(gA1 + k0, lA1);
        GLOAD_LDS16(gB0 + k0, lB0);
        GLOAD_LDS16(gB1 + k0, lB1);
        __syncthreads();
        short8 af[4], bf[4];
        #pragma unroll
        for (int m = 0; m < 4; m++) af[m] = ((const short8*)As)[(arow + m*16)*4 + kh];
        #pragma unroll
        for (int n = 0; n < 4; n++) bf[n] = ((const short8*)Bs)[(brow + n*16)*4 + kh];
        #pragma unroll
        for (int m = 0; m < 4; m++)
            #pragma unroll
            for (int n = 0; n < 4; n++)
                acc[m][n] = __builtin_amdgcn_mfma_f32_16x16x32_bf16(af[m], bf[n], acc[m][n], 0, 0, 0);
        __syncthreads();
    }

    const int crow0 = bm + wm + (lane >> 4)*4;
    const int ccol0 = bn + wn + (lane & 15);
    #pragma unroll
    for (int n = 0; n < 4; n++) {
        const int col = ccol0 + n*16;
        const float bv = bias[col];
        #pragma unroll
        for (int m = 0; m < 4; m++) {
            #pragma unroll
            for (int r = 0; r < 4; r++) {
                int row = crow0 + m*16 + r;
                float v = acc[m][n][r] + bv;
                if (RELU) v = fmaxf(v, 0.f);
                if (OUTBF16)
                    ((__hip_bfloat16*)Cout)[(size_t)row*ldc + col] = __float2bfloat16(v);
                else
                    ((float*)Cout)[(size_t)row*ldc + col] = v;
            }
        }
    }
}

// ---------------- fp32 -> bf16 convert (n % 4 == 0) ----------------
__global__ void f2b(const float* __restrict__ in, __hip_bfloat16* __restrict__ out, int n)
{
    int i = (blockIdx.x*blockDim.x + threadIdx.x)*4;
    if (i >= n) return;
    float4 v = *(const float4*)(in + i);
    __hip_bfloat16 tmp[4];
    tmp[0] = __float2bfloat16(v.x); tmp[1] = __float2bfloat16(v.y);
    tmp[2] = __float2bfloat16(v.z); tmp[3] = __float2bfloat16(v.w);
    *(ushort4*)(out + i) = *(const ushort4*)tmp;
}

// ---------------- embed + scale + pos-enc; writes fp32 + bf16 mirrors ----------------
__global__ void embed_kernel(const float* __restrict__ src,
                             const float* __restrict__ emb_W,
                             const float* __restrict__ emb_b,
                             float* __restrict__ x,
                             __hip_bfloat16* __restrict__ xb)
{
    int row = blockIdx.x;
    int e = threadIdx.x;
    int s = row % SEQ;
    const float* sr = src + (size_t)row*DIN;
    float acc = emb_b[e];
    #pragma unroll
    for (int d = 0; d < DIN; d++) acc += sr[d]*emb_W[e*DIN + d];
    acc *= 16.0f;                    // sqrt(EMB)
    int i2 = e & ~1;
    float div = expf(-(float)i2 * (9.210340371976184f / (float)EMB));
    float ang = (float)s * div;
    float pe = (e & 1) ? cosf(ang) : sinf(ang);
    float v = acc + pe;
    x [(size_t)row*EMB + e] = v;
    xb[(size_t)row*EMB + e] = __float2bfloat16(v);
}

// ---------------- per-(b,h) last-row attention ----------------
// grid (NHEADS, BATCH), 512 threads. Computes q for head h, scores over all 512
// keys, block softmax, per-head softmax row -> amh[(b*H+h)*SEQ], and this head's
// 32 columns of o_last written into the v last row of kv.
__global__ __launch_bounds__(512)
void attn_last_head(const float* __restrict__ x,          // [NTOK, EMB] fp32
                    const float* __restrict__ Wq,         // [EMB, EMB] (q rows of Wqkv[l])
                    const float* __restrict__ bq,
                    __hip_bfloat16* __restrict__ kv,      // [B*S,512] k|v
                    float* __restrict__ amh)              // [B*H, SEQ] for this layer
{
    const int h = blockIdx.x, b = blockIdx.y;
    const int t = threadIdx.x;                 // 0..511
    __shared__ float xlast[EMB];
    __shared__ float qpart[HDIM][17];          // +1 pad: stride 17 kills bank conflicts
    __shared__ float qh[HDIM];
    __shared__ float sc[SEQ];
    __shared__ float red1[8], red2[8];
    __shared__ float opart[16][HDIM];
    __hip_bfloat16* kvb = kv + (size_t)b*SEQ*512;

    if (t < EMB) xlast[t] = x[((size_t)b*SEQ + SEQ-1)*EMB + t];
    __syncthreads();

    // q for this head: 32 dims x 16 k-chunks of 16
    {
        int d = t & 31, c = t >> 5;            // c in 0..15
        const float* wr = Wq + (size_t)(h*HDIM + d)*EMB + c*16;
        float p = 0.f;
        #pragma unroll
        for (int j = 0; j < 16; j++) p += xlast[c*16 + j]*wr[j];
        qpart[d][c] = p;
    }
    __syncthreads();
    if (t < HDIM) {
        float qv = bq[h*HDIM + t];
        #pragma unroll
        for (int c = 0; c < 16; c++) qv += qpart[t][c];
        qh[t] = qv;
    }
    __syncthreads();

    // score for key t (this head only)
    {
        const __hip_bfloat16* krow = kvb + (size_t)t*512 + h*HDIM;
        float s = 0.f;
        #pragma unroll
        for (int vv = 0; vv < 4; vv++) {
            short8 kk = *(const short8*)(krow + vv*8);
            #pragma unroll
            for (int j = 0; j < 8; j++)
                s += qh[vv*8 + j]*__bfloat162float(((const __hip_bfloat16*)&kk)[j]);
        }
        s *= 0.17677669529663687f;             // 1/sqrt(32)
        if (t == SEQ-1) s += -1e9f;            // mask: last row can't attend to itself
        sc[t] = s;
    }
    __syncthreads();

    // block softmax over 512 scores (8 waves)
    {
        int wv = t >> 6, lane = t & 63;
        float m = sc[t];
        #pragma unroll
        for (int o = 32; o; o >>= 1) m = fmaxf(m, __shfl_xor(m, o));
        if (lane == 0) red1[wv] = m;
        __syncthreads();
        m = red1[0];
        #pragma unroll
        for (int i = 1; i < 8; i++) m = fmaxf(m, red1[i]);
        float e = expf(sc[t] - m);
        float s = e;
        #pragma unroll
        for (int o = 32; o; o >>= 1) s += __shfl_xor(s, o);
        if (lane == 0) red2[wv] = s;
        __syncthreads();
        float tot = red2[0]+red2[1]+red2[2]+red2[3]+red2[4]+red2[5]+red2[6]+red2[7];
        float a = e / tot;
        sc[t] = a;
        amh[((size_t)b*NHEADS + h)*SEQ + t] = a;
    }
    __syncthreads();

    // o_last for this head's 32 dims: 16-way k-partition
    {
        int e = t & 31, part = t >> 5;         // part 0..15
        float o = 0.f;
        const __hip_bfloat16* vcol = kvb + 256 + h*HDIM + e;
        for (int k = part*32; k < part*32 + 32; k++)
            o += sc[k]*__bfloat162float(vcol[(size_t)k*512]);
        opart[part][e] = o;
    }
    __syncthreads();
    if (t < HDIM) {
        float o = 0.f;
        #pragma unroll
        for (int p = 0; p < 16; p++) o += opart[p][t];
        kvb[(size_t)(SEQ-1)*512 + 256 + h*HDIM + t] = __float2bfloat16(o);
    }
}

// ---------------- residual + layernorm; writes fp32 + bf16 mirrors ----------------
__global__ void resln(float* __restrict__ x, __hip_bfloat16* __restrict__ xb,
                      const float* __restrict__ t,
                      const float* __restrict__ g, const float* __restrict__ bb)
{
    int row = blockIdx.x;
    int e = threadIdx.x;
    __shared__ float red1[4], red2[4];
    float v = x[(size_t)row*EMB + e] + t[(size_t)row*EMB + e];
    float s = v;
    #pragma unroll
    for (int o = 32; o; o >>= 1) s += __shfl_xor(s, o);
    if ((e & 63) == 0) red1[e >> 6] = s;
    __syncthreads();
    float mean = (red1[0]+red1[1]+red1[2]+red1[3]) * (1.f/EMB);
    float d = v - mean;
    float s2 = d*d;
    #pragma unroll
    for (int o = 32; o; o >>= 1) s2 += __shfl_xor(s2, o);
    if ((e & 63) == 0) red2[e >> 6] = s2;
    __syncthreads();
    float var = (red2[0]+red2[1]+red2[2]+red2[3]) * (1.f/EMB);
    float r = d * (1.f/sqrtf(var + 1e-5f)) * g[e] + bb[e];
    x [(size_t)row*EMB + e] = r;
    xb[(size_t)row*EMB + e] = __float2bfloat16(r);
}

// ---------------- write full attns output [L,B,S,S]; head-avg fused for last rows ----------------
__global__ void write_attns(float* __restrict__ attns, const float* __restrict__ amh_all)
{
    constexpr int PER_ROW = SEQ/4;
    size_t tid = (size_t)blockIdx.x*blockDim.x + threadIdx.x;
    size_t row = tid / PER_ROW;          // l*B*S + b*S + q
    int c4 = (int)(tid % PER_ROW);
    int q = (int)(row % SEQ);
    float4 v = make_float4(0.f,0.f,0.f,0.f);
    if (q == SEQ-1) {
        size_t lb = row / SEQ;           // l*B + b
        const float* base = amh_all + lb*NHEADS*SEQ + c4*4;
        float x0=0.f, x1=0.f, x2=0.f, x3=0.f;
        #pragma unroll
        for (int h = 0; h < NHEADS; h++) {
            const float* r = base + (size_t)h*SEQ;
            x0 += r[0]; x1 += r[1]; x2 += r[2]; x3 += r[3];
        }
        v = make_float4(x0*0.125f, x1*0.125f, x2*0.125f, x3*0.125f);
    } else if ((q >> 2) == c4) {
        ((float*)&v)[q & 3] = 1.f;
    }
    ((float4*)attns)[tid] = v;
}

// ---------------- partial relu-sum over sequence chunks ----------------
__global__ void reduce_relu_part(const float* __restrict__ x, float* __restrict__ rp)
{
    int b = blockIdx.x, ch = blockIdx.y, e = threadIdx.x;
    const float* xb = x + ((size_t)b*SEQ + ch*(SEQ/8))*EMB;
    float s = 0.f;
    for (int i = 0; i < SEQ/8; i++) s += fmaxf(xb[(size_t)i*EMB + e], 0.f);
    rp[(b*8 + ch)*EMB + e] = s;
}

// ---------------- parallel decode + log_softmax: one block per batch row ----------------
__global__ __launch_bounds__(256)
void decode_out2(const float* __restrict__ rp, const float* __restrict__ dec_W,
                 float* __restrict__ out)
{
    int b = blockIdx.x, t = threadIdx.x;
    float r = 0.f;
    #pragma unroll
    for (int ch = 0; ch < 8; ch++) r += rp[(b*8 + ch)*EMB + t];
    float part[NCLS];
    #pragma unroll
    for (int c = 0; c < NCLS; c++) part[c] = r * dec_W[c*EMB + t];
    #pragma unroll
    for (int o = 32; o; o >>= 1)
        #pragma unroll
        for (int c = 0; c < NCLS; c++) part[c] += __shfl_xor(part[c], o);
    __shared__ float red[4][NCLS];
    int wv = t >> 6, lane = t & 63;
    if (lane == 0)
        #pragma unroll
        for (int c = 0; c < NCLS; c++) red[wv][c] = part[c];
    __syncthreads();
    if (t == 0) {
        float lg[NCLS];
        float m = -1e30f;
        #pragma unroll
        for (int c = 0; c < NCLS; c++) {
            lg[c] = (red[0][c]+red[1][c]+red[2][c]+red[3][c]) * (1.f/(float)SEQ);
            m = fmaxf(m, lg[c]);
        }
        float s = 0.f;
        #pragma unroll
        for (int c = 0; c < NCLS; c++) s += expf(lg[c] - m);
        float ls = logf(s);
        #pragma unroll
        for (int c = 0; c < NCLS; c++) out[b*NCLS + c] = lg[c] - m - ls;
    }
}

} // namespace

extern "C" void kernel_launch(void* const* d_in, const int* in_sizes, int n_in,
                              void* d_out, int out_size, void* d_ws, size_t ws_size,
                              hipStream_t stream)
{
    const float* src   = (const float*)d_in[0];
    const float* emb_W = (const float*)d_in[1];
    const float* emb_b = (const float*)d_in[2];
    const float* Wqkv  = (const float*)d_in[3];
    const float* bqkv  = (const float*)d_in[4];
    const float* Wo    = (const float*)d_in[5];
    const float* bo    = (const float*)d_in[6];
    const float* ln1_g = (const float*)d_in[7];
    const float* ln1_b = (const float*)d_in[8];
    const float* ln2_g = (const float*)d_in[9];
    const float* ln2_b = (const float*)d_in[10];
    const float* W1    = (const float*)d_in[11];
    const float* b1    = (const float*)d_in[12];
    const float* W2    = (const float*)d_in[13];
    const float* b2    = (const float*)d_in[14];
    const float* dec_W = (const float*)d_in[15];

    float* out   = (float*)d_out;               // [32,10]
    float* attns = out + BATCH*NCLS;            // [4,32,512,512]

    // workspace layout (~68 MB). kv and the FFN hidden buffer alias the same
    // region (union): never live simultaneously.
    char* ws = (char*)d_ws;
    float*          xbuf = (float*)ws;              ws += (size_t)NTOK*EMB*4;     // 16.78 MB
    __hip_bfloat16* xb16 = (__hip_bfloat16*)ws;     ws += (size_t)NTOK*EMB*2;     //  8.39 MB
    __hip_bfloat16* kvh  = (__hip_bfloat16*)ws;     ws += (size_t)NTOK*FF*2;      // 33.55 MB (kv | hidden)
    float*          tbuf = (float*)ws;              ws += (size_t)NTOK*EMB*4;     // 16.78 MB
    __hip_bfloat16* wq16 = (__hip_bfloat16*)ws;     ws += (size_t)NLAYER*3*EMB*EMB*2;
    __hip_bfloat16* wo16 = (__hip_bfloat16*)ws;     ws += (size_t)NLAYER*EMB*EMB*2;
    __hip_bfloat16* w116 = (__hip_bfloat16*)ws;     ws += (size_t)NLAYER*FF*EMB*2;
    __hip_bfloat16* w216 = (__hip_bfloat16*)ws;     ws += (size_t)NLAYER*EMB*FF*2;
    float*          amall= (float*)ws;              ws += (size_t)NLAYER*BATCH*NHEADS*SEQ*4; // 2.1 MB
    float*          rpart= (float*)ws;              ws += BATCH*8*EMB*4;

    __hip_bfloat16* kv   = kvh;                     // [NTOK, 512]
    __hip_bfloat16* hbuf = kvh;                     // [NTOK, FF]

    // weight conversion fp32 -> bf16
    f2b<<<NLAYER*3*EMB*EMB/4/256, 256, 0, stream>>>(Wqkv, wq16, NLAYER*3*EMB*EMB);
    f2b<<<NLAYER*EMB*EMB/4/256,   256, 0, stream>>>(Wo,   wo16, NLAYER*EMB*EMB);
    f2b<<<NLAYER*FF*EMB/4/256,    256, 0, stream>>>(W1,   w116, NLAYER*FF*EMB);
    f2b<<<NLAYER*EMB*FF/4/256,    256, 0, stream>>>(W2,   w216, NLAYER*EMB*FF);

    embed_kernel<<<NTOK, EMB, 0, stream>>>(src, emb_W, emb_b, xbuf, xb16);

    for (int l = 0; l < NLAYER; l++) {
        // k,v for all tokens (bf16 MFMA): W rows [E..3E)
        gemm_mfma<false, true><<<dim3(512/128, NTOK/128), 256, 0, stream>>>(
            xb16, EMB, wq16 + (size_t)l*3*EMB*EMB + (size_t)EMB*EMB,
            bqkv + (size_t)l*3*EMB + EMB, kv, 512, EMB);

        // fused per-(b,h): q GEMV + scores + softmax + per-head row + o_last
        attn_last_head<<<dim3(NHEADS, BATCH), 512, 0, stream>>>(
            xbuf, Wqkv + (size_t)l*3*EMB*EMB, bqkv + (size_t)l*3*EMB,
            kv, amall + (size_t)l*BATCH*NHEADS*SEQ);

        // o @ Wo^T + bo  (o == v with last row replaced), fp32 out
        gemm_mfma<false, false><<<dim3(EMB/128, NTOK/128), 256, 0, stream>>>(
            kv + 256, 512, wo16 + (size_t)l*EMB*EMB, bo + (size_t)l*EMB, tbuf, EMB, EMB);

        resln<<<NTOK, EMB, 0, stream>>>(xbuf, xb16, tbuf, ln1_g + l*EMB, ln1_b + l*EMB);

        // FFN, full 16384 rows per launch (kv region now dead -> reuse as hidden)
        gemm_mfma<true, true><<<dim3(FF/128, NTOK/128), 256, 0, stream>>>(
            xb16, EMB, w116 + (size_t)l*FF*EMB, b1 + (size_t)l*FF, hbuf, FF, EMB);
        gemm_mfma<false, false><<<dim3(EMB/128, NTOK/128), 256, 0, stream>>>(
            hbuf, FF, w216 + (size_t)l*EMB*FF, b2 + (size_t)l*EMB, tbuf, EMB, FF);

        resln<<<NTOK, EMB, 0, stream>>>(xbuf, xb16, tbuf, ln2_g + l*EMB, ln2_b + l*EMB);
    }

    {
        size_t total_f4 = (size_t)NLAYER*BATCH*SEQ*(SEQ/4);
        int blocks = (int)((total_f4 + 255)/256);
        write_attns<<<blocks, 256, 0, stream>>>(attns, amall);
    }

    reduce_relu_part<<<dim3(BATCH, 8), EMB, 0, stream>>>(xbuf, rpart);
    decode_out2<<<BATCH, 256, 0, stream>>>(rpart, dec_W, out);
}

// Round 7
// 636.805 us; speedup vs baseline: 7.5433x; 1.0662x over previous
//
#include <hip/hip_runtime.h>
#include <hip/hip_bf16.h>
#include <math.h>

namespace {

constexpr int BATCH = 32;
constexpr int SEQ   = 512;
constexpr int DIN   = 9;
constexpr int EMB   = 256;
constexpr int FF    = 1024;
constexpr int NLAYER= 4;
constexpr int NCLS  = 10;
constexpr int NHEADS= 8;
constexpr int HDIM  = 32;
constexpr int NTOK  = BATCH*SEQ;      // 16384

typedef __attribute__((ext_vector_type(8))) short short8;
typedef __attribute__((ext_vector_type(4))) float floatx4;

#define GLOAD_LDS16(g, l) __builtin_amdgcn_global_load_lds( \
    (const __attribute__((address_space(1))) unsigned*)(g), \
    (__attribute__((address_space(3))) unsigned*)(l), 16, 0, 0)

// ---------------- bf16 MFMA GEMM: C[M,N] = A[M,K](bf16) @ W[N,K](bf16)^T + bias ----------------
// 128x128 tile, BK=32, 4 waves (2x2), each wave owns a 64x64 sub-tile.
template<bool RELU>
__global__ __launch_bounds__(256)
void gemm_mfma(const __hip_bfloat16* __restrict__ A, int lda,
               const __hip_bfloat16* __restrict__ W,     // [N,K] row-major (= B^T)
               const float* __restrict__ bias,
               __hip_bfloat16* __restrict__ Cout, int ldc,
               int K)
{
    __shared__ __hip_bfloat16 As[128*32];   // [row][k], 64B/row
    __shared__ __hip_bfloat16 Bs[128*32];
    const int bm = blockIdx.y*128, bn = blockIdx.x*128;
    const int tid  = threadIdx.x;
    const int lane = tid & 63;
    const int w    = tid >> 6;
    const int wm   = (w >> 1)*64, wn = (w & 1)*64;

    floatx4 acc[4][4] = {};

    const int srow = w*32 + (lane >> 2);
    const int scol = (lane & 3)*8;
    const __hip_bfloat16* gA0 = A + (size_t)(bm + srow)*lda + scol;
    const __hip_bfloat16* gA1 = A + (size_t)(bm + srow + 16)*lda + scol;
    const __hip_bfloat16* gB0 = W + (size_t)(bn + srow)*K + scol;
    const __hip_bfloat16* gB1 = W + (size_t)(bn + srow + 16)*K + scol;
    __hip_bfloat16* lA0 = As + (w*2    )*512;
    __hip_bfloat16* lA1 = As + (w*2 + 1)*512;
    __hip_bfloat16* lB0 = Bs + (w*2    )*512;
    __hip_bfloat16* lB1 = Bs + (w*2 + 1)*512;

    const int arow = wm + (lane & 15);
    const int brow = wn + (lane & 15);
    const int kh   = lane >> 4;

    for (int k0 = 0; k0 < K; k0 += 32) {
        GLOAD_LDS16(gA0 + k0, lA0);
        GLOAD_LDS16(gA1 + k0, lA1);
        GLOAD_LDS16(gB0 + k0, lB0);
        GLOAD_LDS16(gB1 + k0, lB1);
        __syncthreads();
        short8 af[4], bf[4];
        #pragma unroll
        for (int m = 0; m < 4; m++) af[m] = ((const short8*)As)[(arow + m*16)*4 + kh];
        #pragma unroll
        for (int n = 0; n < 4; n++) bf[n] = ((const short8*)Bs)[(brow + n*16)*4 + kh];
        #pragma unroll
        for (int m = 0; m < 4; m++)
            #pragma unroll
            for (int n = 0; n < 4; n++)
                acc[m][n] = __builtin_amdgcn_mfma_f32_16x16x32_bf16(af[m], bf[n], acc[m][n], 0, 0, 0);
        __syncthreads();
    }

    const int crow0 = bm + wm + (lane >> 4)*4;
    const int ccol0 = bn + wn + (lane & 15);
    #pragma unroll
    for (int n = 0; n < 4; n++) {
        const int col = ccol0 + n*16;
        const float bv = bias[col];
        #pragma unroll
        for (int m = 0; m < 4; m++) {
            #pragma unroll
            for (int r = 0; r < 4; r++) {
                int row = crow0 + m*16 + r;
                float v = acc[m][n][r] + bv;
                if (RELU) v = fmaxf(v, 0.f);
                Cout[(size_t)row*ldc + col] = __float2bfloat16(v);
            }
        }
    }
}

// ---------------- fused GEMM + bias + residual + LayerNorm ----------------
// C[M,256] = A[M,K] @ W[256,K]^T + bias;  xnew = LN(xres + C)*g + b
// 64x256 tile, 4 waves (wave w owns cols w*64..w*64+63, all 64 rows).
__global__ __launch_bounds__(256)
void gemm_ln(const __hip_bfloat16* __restrict__ A, int lda,
             const __hip_bfloat16* __restrict__ W,     // [256,K]
             const float* __restrict__ bias,
             const float* __restrict__ g,
             const float* __restrict__ bb,
             float* __restrict__ xres,                 // in/out fp32 [NTOK,256]
             __hip_bfloat16* __restrict__ xb16,        // out bf16 mirror
             int K)
{
    __shared__ __hip_bfloat16 As[64*32];               // 4 KB
    __shared__ __hip_bfloat16 Bs[256*32];              // 16 KB
    __shared__ float ssum[4][64], sqsum[4][64];
    const int bm   = blockIdx.x*64;
    const int tid  = threadIdx.x;
    const int lane = tid & 63;
    const int w    = tid >> 6;
    const int rg   = lane >> 4;                        // 0..3
    const int cl   = lane & 15;

    floatx4 acc[4][4] = {};

    // staging: 20 chunks of 1024B (A: 0..3, B: 4..19); wave w stages 5w..5w+4
    const __hip_bfloat16* gsrc[5];
    __hip_bfloat16* ldst[5];
    #pragma unroll
    for (int cc = 0; cc < 5; cc++) {
        int c = 5*w + cc;
        if (c < 4) {
            gsrc[cc] = A + (size_t)(bm + c*16 + (lane >> 2))*lda + (lane & 3)*8;
            ldst[cc] = As + c*512;
        } else {
            int cb = c - 4;
            gsrc[cc] = W + (size_t)(cb*16 + (lane >> 2))*K + (lane & 3)*8;
            ldst[cc] = Bs + cb*512;
        }
    }

    const int kh = lane >> 4;
    for (int k0 = 0; k0 < K; k0 += 32) {
        #pragma unroll
        for (int cc = 0; cc < 5; cc++) GLOAD_LDS16(gsrc[cc] + k0, ldst[cc]);
        __syncthreads();
        short8 af[4], bf[4];
        #pragma unroll
        for (int m = 0; m < 4; m++) af[m] = ((const short8*)As)[(m*16 + cl)*4 + kh];
        #pragma unroll
        for (int n = 0; n < 4; n++) bf[n] = ((const short8*)Bs)[(w*64 + n*16 + cl)*4 + kh];
        #pragma unroll
        for (int m = 0; m < 4; m++)
            #pragma unroll
            for (int n = 0; n < 4; n++)
                acc[m][n] = __builtin_amdgcn_mfma_f32_16x16x32_bf16(af[m], bf[n], acc[m][n], 0, 0, 0);
        __syncthreads();
    }

    // epilogue: t = xres + (acc + bias), then LN over the 256-col row
    const int colbase = w*64 + cl;
    float bv[4], gv[4], bbv[4];
    #pragma unroll
    for (int n = 0; n < 4; n++) {
        bv[n] = bias[colbase + n*16];
        gv[n] = g[colbase + n*16];
        bbv[n] = bb[colbase + n*16];
    }

    #pragma unroll
    for (int m = 0; m < 4; m++) {
        #pragma unroll
        for (int r = 0; r < 4; r++) {
            const int row = m*16 + rg*4 + r;
            const float* xr = xres + (size_t)(bm + row)*EMB;
            #pragma unroll
            for (int n = 0; n < 4; n++)
                acc[m][n][r] += bv[n] + xr[colbase + n*16];
        }
    }

    // per-row sums (16 lanes x 4 regs per row) via shfl_xor within 16-lane group
    #pragma unroll
    for (int m = 0; m < 4; m++) {
        #pragma unroll
        for (int r = 0; r < 4; r++) {
            float s = 0.f, q = 0.f;
            #pragma unroll
            for (int n = 0; n < 4; n++) { float v = acc[m][n][r]; s += v; q += v*v; }
            #pragma unroll
            for (int o = 1; o < 16; o <<= 1) { s += __shfl_xor(s, o); q += __shfl_xor(q, o); }
            if (cl == 0) { ssum[w][m*16 + rg*4 + r] = s; sqsum[w][m*16 + rg*4 + r] = q; }
        }
    }
    __syncthreads();

    #pragma unroll
    for (int m = 0; m < 4; m++) {
        #pragma unroll
        for (int r = 0; r < 4; r++) {
            const int row = m*16 + rg*4 + r;
            float S = ssum[0][row] + ssum[1][row] + ssum[2][row] + ssum[3][row];
            float Q = sqsum[0][row] + sqsum[1][row] + sqsum[2][row] + sqsum[3][row];
            float mean = S * (1.f/EMB);
            float var  = Q * (1.f/EMB) - mean*mean;
            float rstd = 1.f / sqrtf(var + 1e-5f);
            float* xr = xres + (size_t)(bm + row)*EMB;
            __hip_bfloat16* xbr = xb16 + (size_t)(bm + row)*EMB;
            #pragma unroll
            for (int n = 0; n < 4; n++) {
                float v = (acc[m][n][r] - mean)*rstd*gv[n] + bbv[n];
                xr [colbase + n*16] = v;
                xbr[colbase + n*16] = __float2bfloat16(v);
            }
        }
    }
}

// ---------------- fp32 -> bf16 convert (n % 4 == 0) ----------------
__global__ void f2b(const float* __restrict__ in, __hip_bfloat16* __restrict__ out, int n)
{
    int i = (blockIdx.x*blockDim.x + threadIdx.x)*4;
    if (i >= n) return;
    float4 v = *(const float4*)(in + i);
    __hip_bfloat16 tmp[4];
    tmp[0] = __float2bfloat16(v.x); tmp[1] = __float2bfloat16(v.y);
    tmp[2] = __float2bfloat16(v.z); tmp[3] = __float2bfloat16(v.w);
    *(ushort4*)(out + i) = *(const ushort4*)tmp;
}

// ---------------- embed + scale + pos-enc; writes fp32 + bf16 mirrors ----------------
__global__ void embed_kernel(const float* __restrict__ src,
                             const float* __restrict__ emb_W,
                             const float* __restrict__ emb_b,
                             float* __restrict__ x,
                             __hip_bfloat16* __restrict__ xb)
{
    int row = blockIdx.x;
    int e = threadIdx.x;
    int s = row % SEQ;
    const float* sr = src + (size_t)row*DIN;
    float acc = emb_b[e];
    #pragma unroll
    for (int d = 0; d < DIN; d++) acc += sr[d]*emb_W[e*DIN + d];
    acc *= 16.0f;                    // sqrt(EMB)
    int i2 = e & ~1;
    float div = expf(-(float)i2 * (9.210340371976184f / (float)EMB));
    float ang = (float)s * div;
    float pe = (e & 1) ? cosf(ang) : sinf(ang);
    float v = acc + pe;
    x [(size_t)row*EMB + e] = v;
    xb[(size_t)row*EMB + e] = __float2bfloat16(v);
}

// ---------------- per-(b,h) last-row attention (contiguous k/v buffers) ----------------
__global__ __launch_bounds__(512)
void attn_last_head(const float* __restrict__ x,          // [NTOK, EMB] fp32
                    const float* __restrict__ Wq,         // [EMB, EMB] (q rows of Wqkv[l])
                    const float* __restrict__ bq,
                    const __hip_bfloat16* __restrict__ kbuf, // [B*S,256]
                    __hip_bfloat16* __restrict__ vbuf,       // [B*S,256]
                    float* __restrict__ amh)              // [B*H, SEQ] for this layer
{
    const int h = blockIdx.x, b = blockIdx.y;
    const int t = threadIdx.x;                 // 0..511
    __shared__ float xlast[EMB];
    __shared__ float qpart[HDIM][17];
    __shared__ float qh[HDIM];
    __shared__ float sc[SEQ];
    __shared__ float red1[8], red2[8];
    __shared__ float opart[16][HDIM];

    if (t < EMB) xlast[t] = x[((size_t)b*SEQ + SEQ-1)*EMB + t];
    __syncthreads();

    {
        int d = t & 31, c = t >> 5;            // c in 0..15
        const float* wr = Wq + (size_t)(h*HDIM + d)*EMB + c*16;
        float p = 0.f;
        #pragma unroll
        for (int j = 0; j < 16; j++) p += xlast[c*16 + j]*wr[j];
        qpart[d][c] = p;
    }
    __syncthreads();
    if (t < HDIM) {
        float qv = bq[h*HDIM + t];
        #pragma unroll
        for (int c = 0; c < 16; c++) qv += qpart[t][c];
        qh[t] = qv;
    }
    __syncthreads();

    // score for key t (this head only)
    {
        const __hip_bfloat16* krow = kbuf + ((size_t)b*SEQ + t)*EMB + h*HDIM;
        float s = 0.f;
        #pragma unroll
        for (int vv = 0; vv < 4; vv++) {
            short8 kk = *(const short8*)(krow + vv*8);
            #pragma unroll
            for (int j = 0; j < 8; j++)
                s += qh[vv*8 + j]*__bfloat162float(((const __hip_bfloat16*)&kk)[j]);
        }
        s *= 0.17677669529663687f;
        if (t == SEQ-1) s += -1e9f;
        sc[t] = s;
    }
    __syncthreads();

    // block softmax over 512 scores (8 waves)
    {
        int wv = t >> 6, lane = t & 63;
        float m = sc[t];
        #pragma unroll
        for (int o = 32; o; o >>= 1) m = fmaxf(m, __shfl_xor(m, o));
        if (lane == 0) red1[wv] = m;
        __syncthreads();
        m = red1[0];
        #pragma unroll
        for (int i = 1; i < 8; i++) m = fmaxf(m, red1[i]);
        float e = expf(sc[t] - m);
        float s = e;
        #pragma unroll
        for (int o = 32; o; o >>= 1) s += __shfl_xor(s, o);
        if (lane == 0) red2[wv] = s;
        __syncthreads();
        float tot = red2[0]+red2[1]+red2[2]+red2[3]+red2[4]+red2[5]+red2[6]+red2[7];
        float a = e / tot;
        sc[t] = a;
        amh[((size_t)b*NHEADS + h)*SEQ + t] = a;
    }
    __syncthreads();

    // o_last for this head's 32 dims: 16-way k-partition
    {
        int e = t & 31, part = t >> 5;
        float o = 0.f;
        const __hip_bfloat16* vc = vbuf + (size_t)b*SEQ*EMB + h*HDIM + e;
        for (int k = part*32; k < part*32 + 32; k++)
            o += sc[k]*__bfloat162float(vc[(size_t)k*EMB]);
        opart[part][e] = o;
    }
    __syncthreads();
    if (t < HDIM) {
        float o = 0.f;
        #pragma unroll
        for (int p = 0; p < 16; p++) o += opart[p][t];
        vbuf[((size_t)b*SEQ + SEQ-1)*EMB + h*HDIM + t] = __float2bfloat16(o);
    }
}

// ---------------- write full attns output [L,B,S,S]; head-avg fused for last rows ----------------
__global__ void write_attns(float* __restrict__ attns, const float* __restrict__ amh_all)
{
    constexpr int PER_ROW = SEQ/4;
    size_t tid = (size_t)blockIdx.x*blockDim.x + threadIdx.x;
    size_t row = tid / PER_ROW;
    int c4 = (int)(tid % PER_ROW);
    int q = (int)(row % SEQ);
    float4 v = make_float4(0.f,0.f,0.f,0.f);
    if (q == SEQ-1) {
        size_t lb = row / SEQ;
        const float* base = amh_all + lb*NHEADS*SEQ + c4*4;
        float x0=0.f, x1=0.f, x2=0.f, x3=0.f;
        #pragma unroll
        for (int h = 0; h < NHEADS; h++) {
            const float* r = base + (size_t)h*SEQ;
            x0 += r[0]; x1 += r[1]; x2 += r[2]; x3 += r[3];
        }
        v = make_float4(x0*0.125f, x1*0.125f, x2*0.125f, x3*0.125f);
    } else if ((q >> 2) == c4) {
        ((float*)&v)[q & 3] = 1.f;
    }
    ((float4*)attns)[tid] = v;
}

// ---------------- partial relu-sum over sequence chunks ----------------
__global__ void reduce_relu_part(const float* __restrict__ x, float* __restrict__ rp)
{
    int b = blockIdx.x, ch = blockIdx.y, e = threadIdx.x;
    const float* xb = x + ((size_t)b*SEQ + ch*(SEQ/8))*EMB;
    float s = 0.f;
    for (int i = 0; i < SEQ/8; i++) s += fmaxf(xb[(size_t)i*EMB + e], 0.f);
    rp[(b*8 + ch)*EMB + e] = s;
}

// ---------------- parallel decode + log_softmax: one block per batch row ----------------
__global__ __launch_bounds__(256)
void decode_out2(const float* __restrict__ rp, const float* __restrict__ dec_W,
                 float* __restrict__ out)
{
    int b = blockIdx.x, t = threadIdx.x;
    float r = 0.f;
    #pragma unroll
    for (int ch = 0; ch < 8; ch++) r += rp[(b*8 + ch)*EMB + t];
    float part[NCLS];
    #pragma unroll
    for (int c = 0; c < NCLS; c++) part[c] = r * dec_W[c*EMB + t];
    #pragma unroll
    for (int o = 32; o; o >>= 1)
        #pragma unroll
        for (int c = 0; c < NCLS; c++) part[c] += __shfl_xor(part[c], o);
    __shared__ float red[4][NCLS];
    int wv = t >> 6, lane = t & 63;
    if (lane == 0)
        #pragma unroll
        for (int c = 0; c < NCLS; c++) red[wv][c] = part[c];
    __syncthreads();
    if (t == 0) {
        float lg[NCLS];
        float m = -1e30f;
        #pragma unroll
        for (int c = 0; c < NCLS; c++) {
            lg[c] = (red[0][c]+red[1][c]+red[2][c]+red[3][c]) * (1.f/(float)SEQ);
            m = fmaxf(m, lg[c]);
        }
        float s = 0.f;
        #pragma unroll
        for (int c = 0; c < NCLS; c++) s += expf(lg[c] - m);
        float ls = logf(s);
        #pragma unroll
        for (int c = 0; c < NCLS; c++) out[b*NCLS + c] = lg[c] - m - ls;
    }
}

} // namespace

extern "C" void kernel_launch(void* const* d_in, const int* in_sizes, int n_in,
                              void* d_out, int out_size, void* d_ws, size_t ws_size,
                              hipStream_t stream)
{
    const float* src   = (const float*)d_in[0];
    const float* emb_W = (const float*)d_in[1];
    const float* emb_b = (const float*)d_in[2];
    const float* Wqkv  = (const float*)d_in[3];
    const float* bqkv  = (const float*)d_in[4];
    const float* Wo    = (const float*)d_in[5];
    const float* bo    = (const float*)d_in[6];
    const float* ln1_g = (const float*)d_in[7];
    const float* ln1_b = (const float*)d_in[8];
    const float* ln2_g = (const float*)d_in[9];
    const float* ln2_b = (const float*)d_in[10];
    const float* W1    = (const float*)d_in[11];
    const float* b1    = (const float*)d_in[12];
    const float* W2    = (const float*)d_in[13];
    const float* b2    = (const float*)d_in[14];
    const float* dec_W = (const float*)d_in[15];

    float* out   = (float*)d_out;               // [32,10]
    float* attns = out + BATCH*NCLS;            // [4,32,512,512]

    // workspace layout (~84 MB), no aliasing
    char* ws = (char*)d_ws;
    float*          xbuf = (float*)ws;              ws += (size_t)NTOK*EMB*4;     // 16.78 MB
    __hip_bfloat16* xb16 = (__hip_bfloat16*)ws;     ws += (size_t)NTOK*EMB*2;     //  8.39 MB
    __hip_bfloat16* kbuf = (__hip_bfloat16*)ws;     ws += (size_t)NTOK*EMB*2;     //  8.39 MB
    __hip_bfloat16* vbuf = (__hip_bfloat16*)ws;     ws += (size_t)NTOK*EMB*2;     //  8.39 MB
    __hip_bfloat16* hbuf = (__hip_bfloat16*)ws;     ws += (size_t)NTOK*FF*2;      // 33.55 MB
    __hip_bfloat16* wq16 = (__hip_bfloat16*)ws;     ws += (size_t)NLAYER*3*EMB*EMB*2;
    __hip_bfloat16* wo16 = (__hip_bfloat16*)ws;     ws += (size_t)NLAYER*EMB*EMB*2;
    __hip_bfloat16* w116 = (__hip_bfloat16*)ws;     ws += (size_t)NLAYER*FF*EMB*2;
    __hip_bfloat16* w216 = (__hip_bfloat16*)ws;     ws += (size_t)NLAYER*EMB*FF*2;
    float*          amall= (float*)ws;              ws += (size_t)NLAYER*BATCH*NHEADS*SEQ*4; // 2.1 MB
    float*          rpart= (float*)ws;              ws += BATCH*8*EMB*4;

    // weight conversion fp32 -> bf16
    f2b<<<NLAYER*3*EMB*EMB/4/256, 256, 0, stream>>>(Wqkv, wq16, NLAYER*3*EMB*EMB);
    f2b<<<NLAYER*EMB*EMB/4/256,   256, 0, stream>>>(Wo,   wo16, NLAYER*EMB*EMB);
    f2b<<<NLAYER*FF*EMB/4/256,    256, 0, stream>>>(W1,   w116, NLAYER*FF*EMB);
    f2b<<<NLAYER*EMB*FF/4/256,    256, 0, stream>>>(W2,   w216, NLAYER*EMB*FF);

    embed_kernel<<<NTOK, EMB, 0, stream>>>(src, emb_W, emb_b, xbuf, xb16);

    for (int l = 0; l < NLAYER; l++) {
        const __hip_bfloat16* wql = wq16 + (size_t)l*3*EMB*EMB;
        const float* bql = bqkv + (size_t)l*3*EMB;

        // k and v projections (contiguous outputs)
        gemm_mfma<false><<<dim3(EMB/128, NTOK/128), 256, 0, stream>>>(
            xb16, EMB, wql + (size_t)EMB*EMB,   bql + EMB,   kbuf, EMB, EMB);
        gemm_mfma<false><<<dim3(EMB/128, NTOK/128), 256, 0, stream>>>(
            xb16, EMB, wql + (size_t)2*EMB*EMB, bql + 2*EMB, vbuf, EMB, EMB);

        // fused per-(b,h): q GEMV + scores + softmax + per-head row + o_last
        attn_last_head<<<dim3(NHEADS, BATCH), 512, 0, stream>>>(
            xbuf, Wqkv + (size_t)l*3*EMB*EMB, bqkv + (size_t)l*3*EMB,
            kbuf, vbuf, amall + (size_t)l*BATCH*NHEADS*SEQ);

        // Wo GEMM + bias + residual + LN1 (writes xbuf/xb16)
        gemm_ln<<<NTOK/64, 256, 0, stream>>>(
            vbuf, EMB, wo16 + (size_t)l*EMB*EMB, bo + (size_t)l*EMB,
            ln1_g + l*EMB, ln1_b + l*EMB, xbuf, xb16, EMB);

        // FFN1 (relu, bf16 out)
        gemm_mfma<true><<<dim3(FF/128, NTOK/128), 256, 0, stream>>>(
            xb16, EMB, w116 + (size_t)l*FF*EMB, b1 + (size_t)l*FF, hbuf, FF, EMB);

        // FFN2 GEMM + bias + residual + LN2
        gemm_ln<<<NTOK/64, 256, 0, stream>>>(
            hbuf, FF, w216 + (size_t)l*EMB*FF, b2 + (size_t)l*EMB,
            ln2_g + l*EMB, ln2_b + l*EMB, xbuf, xb16, FF);
    }

    {
        size_t total_f4 = (size_t)NLAYER*BATCH*SEQ*(SEQ/4);
        int blocks = (int)((total_f4 + 255)/256);
        write_attns<<<blocks, 256, 0, stream>>>(attns, amall);
    }

    reduce_relu_part<<<dim3(BATCH, 8), EMB, 0, stream>>>(xbuf, rpart);
    decode_out2<<<BATCH, 256, 0, stream>>>(rpart, dec_W, out);
}

// Round 8
// 620.153 us; speedup vs baseline: 7.7459x; 1.0269x over previous
//
#include <hip/hip_runtime.h>
#include <hip/hip_bf16.h>
#include <math.h>

namespace {

constexpr int BATCH = 32;
constexpr int SEQ   = 512;
constexpr int DIN   = 9;
constexpr int EMB   = 256;
constexpr int FF    = 1024;
constexpr int NLAYER= 4;
constexpr int NCLS  = 10;
constexpr int NHEADS= 8;
constexpr int HDIM  = 32;
constexpr int NTOK  = BATCH*SEQ;      // 16384

typedef __attribute__((ext_vector_type(8))) short short8;
typedef __attribute__((ext_vector_type(4))) float floatx4;

#define GLOAD_LDS16(g, l) __builtin_amdgcn_global_load_lds( \
    (const __attribute__((address_space(1))) unsigned*)(g), \
    (__attribute__((address_space(3))) unsigned*)(l), 16, 0, 0)

// ---------------- bf16 MFMA GEMM, 2-phase double-buffered ----------------
// C[M,N] = A[M,K] @ W[N,K]^T + bias. 128x128 tile, BK=32, 4 waves (2x2).
// KV=true: N=512 fused k|v projection — block col bn<256 -> C0 (k), else C1 (v).
template<bool RELU, bool KV>
__global__ __launch_bounds__(256)
void gemm_mfma(const __hip_bfloat16* __restrict__ A, int lda,
               const __hip_bfloat16* __restrict__ W,     // [N,K] row-major
               const float* __restrict__ bias,
               __hip_bfloat16* __restrict__ C0,
               __hip_bfloat16* __restrict__ C1,
               int ldc, int K)
{
    __shared__ __hip_bfloat16 As[2*128*32];
    __shared__ __hip_bfloat16 Bs[2*128*32];
    const int bm = blockIdx.y*128, bn = blockIdx.x*128;
    const int tid  = threadIdx.x;
    const int lane = tid & 63;
    const int w    = tid >> 6;
    const int wm   = (w >> 1)*64, wn = (w & 1)*64;

    floatx4 acc[4][4] = {};

    const int srow = w*32 + (lane >> 2);
    const int scol = (lane & 3)*8;
    const __hip_bfloat16* gA0 = A + (size_t)(bm + srow)*lda + scol;
    const __hip_bfloat16* gA1 = A + (size_t)(bm + srow + 16)*lda + scol;
    const __hip_bfloat16* gB0 = W + (size_t)(bn + srow)*K + scol;
    const __hip_bfloat16* gB1 = W + (size_t)(bn + srow + 16)*K + scol;
    const int l0 = (w*2)*512, l1 = (w*2 + 1)*512;

#define GM_STAGE(buf, k0) do { \
    GLOAD_LDS16(gA0 + (k0), As + (buf)*4096 + l0); \
    GLOAD_LDS16(gA1 + (k0), As + (buf)*4096 + l1); \
    GLOAD_LDS16(gB0 + (k0), Bs + (buf)*4096 + l0); \
    GLOAD_LDS16(gB1 + (k0), Bs + (buf)*4096 + l1); } while (0)

    const int arow = wm + (lane & 15);
    const int brow = wn + (lane & 15);
    const int kh   = lane >> 4;
    const int nt   = K >> 5;

    GM_STAGE(0, 0);
    __syncthreads();
    for (int t = 0; t < nt; t++) {
        const int cur = t & 1;
        if (t + 1 < nt) GM_STAGE(cur ^ 1, (t+1)*32);   // issue next-tile loads early
        const short8* Ab = (const short8*)(As + cur*4096);
        const short8* Bb = (const short8*)(Bs + cur*4096);
        short8 af[4], bf[4];
        #pragma unroll
        for (int m = 0; m < 4; m++) af[m] = Ab[(arow + m*16)*4 + kh];
        #pragma unroll
        for (int n = 0; n < 4; n++) bf[n] = Bb[(brow + n*16)*4 + kh];
        #pragma unroll
        for (int m = 0; m < 4; m++)
            #pragma unroll
            for (int n = 0; n < 4; n++)
                acc[m][n] = __builtin_amdgcn_mfma_f32_16x16x32_bf16(af[m], bf[n], acc[m][n], 0, 0, 0);
        __syncthreads();                               // drains next-tile loads too
    }
#undef GM_STAGE

    __hip_bfloat16* Cb;
    int cb;
    if (KV && bn >= 256) { Cb = C1; cb = bn - 256; }
    else                 { Cb = C0; cb = bn; }

    const int crow0 = bm + wm + (lane >> 4)*4;
    #pragma unroll
    for (int n = 0; n < 4; n++) {
        const int coln = wn + (lane & 15) + n*16;
        const float bv = bias[bn + coln];
        #pragma unroll
        for (int m = 0; m < 4; m++) {
            #pragma unroll
            for (int r = 0; r < 4; r++) {
                int row = crow0 + m*16 + r;
                float v = acc[m][n][r] + bv;
                if (RELU) v = fmaxf(v, 0.f);
                Cb[(size_t)row*ldc + cb + coln] = __float2bfloat16(v);
            }
        }
    }
}

// ---------------- fused GEMM + bias + residual + LayerNorm (wave-local LN) ----------------
// C[M,256] = A[M,K] @ W[256,K]^T + bias; xnew = LN(xres + C)*g + b.
// BM=64, BN=256, BK=32, 4 waves; wave w owns rows w*16..w*16+15 x ALL 256 cols
// -> acc[16], LN reduction fully in-wave (in-reg n-sum + shfl over 16-lane group).
__global__ __launch_bounds__(256)
void gemm_ln(const __hip_bfloat16* __restrict__ A, int lda,
             const __hip_bfloat16* __restrict__ W,     // [256,K]
             const float* __restrict__ bias,
             const float* __restrict__ g,
             const float* __restrict__ bb,
             float* __restrict__ xres,                 // in/out fp32 [NTOK,256]
             __hip_bfloat16* __restrict__ xb16,        // out bf16 mirror
             int K)
{
    __shared__ __hip_bfloat16 As[2*64*32];             // 2 x 4 KB
    __shared__ __hip_bfloat16 Bs[2*256*32];            // 2 x 16 KB
    const int bm   = blockIdx.x*64;
    const int tid  = threadIdx.x;
    const int lane = tid & 63;
    const int w    = tid >> 6;
    const int cl   = lane & 15;
    const int rg   = lane >> 4;                        // 0..3

    floatx4 acc[16] = {};

    // staging: A 4 chunks (wave w stages chunk w), B 16 chunks (wave w stages 4w..4w+3)
    const __hip_bfloat16* gA = A + (size_t)(bm + w*16 + (lane >> 2))*lda + (lane & 3)*8;
    const __hip_bfloat16* gB0 = W + (size_t)((4*w+0)*16 + (lane >> 2))*K + (lane & 3)*8;
    const __hip_bfloat16* gB1 = W + (size_t)((4*w+1)*16 + (lane >> 2))*K + (lane & 3)*8;
    const __hip_bfloat16* gB2 = W + (size_t)((4*w+2)*16 + (lane >> 2))*K + (lane & 3)*8;
    const __hip_bfloat16* gB3 = W + (size_t)((4*w+3)*16 + (lane >> 2))*K + (lane & 3)*8;

#define GL_STAGE(buf, k0) do { \
    GLOAD_LDS16(gA  + (k0), As + (buf)*2048 + w*512); \
    GLOAD_LDS16(gB0 + (k0), Bs + (buf)*8192 + (4*w+0)*512); \
    GLOAD_LDS16(gB1 + (k0), Bs + (buf)*8192 + (4*w+1)*512); \
    GLOAD_LDS16(gB2 + (k0), Bs + (buf)*8192 + (4*w+2)*512); \
    GLOAD_LDS16(gB3 + (k0), Bs + (buf)*8192 + (4*w+3)*512); } while (0)

    const int kh = lane >> 4;
    const int nt = K >> 5;

    GL_STAGE(0, 0);
    __syncthreads();
    for (int t = 0; t < nt; t++) {
        const int cur = t & 1;
        if (t + 1 < nt) GL_STAGE(cur ^ 1, (t+1)*32);
        const short8* Ab = (const short8*)(As + cur*2048);
        const short8* Bb = (const short8*)(Bs + cur*8192);
        short8 af = Ab[(w*16 + cl)*4 + kh];
        #pragma unroll
        for (int n = 0; n < 16; n++) {
            short8 bf = Bb[(n*16 + cl)*4 + kh];
            acc[n] = __builtin_amdgcn_mfma_f32_16x16x32_bf16(af, bf, acc[n], 0, 0, 0);
        }
        __syncthreads();
    }
#undef GL_STAGE

    // epilogue: rows w*16 + rg*4 + r, cols n*16 + cl. Wave-local LN.
    float bv[16], gv[16], bbv[16];
    #pragma unroll
    for (int n = 0; n < 16; n++) {
        const int c = n*16 + cl;
        bv[n] = bias[c]; gv[n] = g[c]; bbv[n] = bb[c];
    }
    #pragma unroll
    for (int r = 0; r < 4; r++) {
        const int row = bm + w*16 + rg*4 + r;
        float* xr = xres + (size_t)row*EMB;
        __hip_bfloat16* xbr = xb16 + (size_t)row*EMB;
        float vals[16];
        float S = 0.f, Q = 0.f;
        #pragma unroll
        for (int n = 0; n < 16; n++) {
            float v = acc[n][r] + bv[n] + xr[n*16 + cl];
            vals[n] = v; S += v; Q += v*v;
        }
        #pragma unroll
        for (int o = 1; o < 16; o <<= 1) { S += __shfl_xor(S, o); Q += __shfl_xor(Q, o); }
        const float mean = S * (1.f/EMB);
        const float var  = Q * (1.f/EMB) - mean*mean;
        const float rstd = 1.f / sqrtf(var + 1e-5f);
        #pragma unroll
        for (int n = 0; n < 16; n++) {
            float v = (vals[n] - mean)*rstd*gv[n] + bbv[n];
            xr [n*16 + cl] = v;
            xbr[n*16 + cl] = __float2bfloat16(v);
        }
    }
}

// ---------------- fp32 -> bf16 convert (n % 4 == 0) ----------------
__global__ void f2b(const float* __restrict__ in, __hip_bfloat16* __restrict__ out, int n)
{
    int i = (blockIdx.x*blockDim.x + threadIdx.x)*4;
    if (i >= n) return;
    float4 v = *(const float4*)(in + i);
    __hip_bfloat16 tmp[4];
    tmp[0] = __float2bfloat16(v.x); tmp[1] = __float2bfloat16(v.y);
    tmp[2] = __float2bfloat16(v.z); tmp[3] = __float2bfloat16(v.w);
    *(ushort4*)(out + i) = *(const ushort4*)tmp;
}

// ---------------- embed + scale + pos-enc; writes fp32 + bf16 mirrors ----------------
__global__ void embed_kernel(const float* __restrict__ src,
                             const float* __restrict__ emb_W,
                             const float* __restrict__ emb_b,
                             float* __restrict__ x,
                             __hip_bfloat16* __restrict__ xb)
{
    int row = blockIdx.x;
    int e = threadIdx.x;
    int s = row % SEQ;
    const float* sr = src + (size_t)row*DIN;
    float acc = emb_b[e];
    #pragma unroll
    for (int d = 0; d < DIN; d++) acc += sr[d]*emb_W[e*DIN + d];
    acc *= 16.0f;                    // sqrt(EMB)
    int i2 = e & ~1;
    float div = expf(-(float)i2 * (9.210340371976184f / (float)EMB));
    float ang = (float)s * div;
    float pe = (e & 1) ? cosf(ang) : sinf(ang);
    float v = acc + pe;
    x [(size_t)row*EMB + e] = v;
    xb[(size_t)row*EMB + e] = __float2bfloat16(v);
}

// ---------------- per-(b,h) last-row attention (contiguous k/v buffers) ----------------
__global__ __launch_bounds__(512)
void attn_last_head(const float* __restrict__ x,          // [NTOK, EMB] fp32
                    const float* __restrict__ Wq,         // [EMB, EMB] (q rows of Wqkv[l])
                    const float* __restrict__ bq,
                    const __hip_bfloat16* __restrict__ kbuf, // [B*S,256]
                    __hip_bfloat16* __restrict__ vbuf,       // [B*S,256]
                    float* __restrict__ amh)              // [B*H, SEQ] for this layer
{
    const int h = blockIdx.x, b = blockIdx.y;
    const int t = threadIdx.x;                 // 0..511
    __shared__ float xlast[EMB];
    __shared__ float qpart[HDIM][17];
    __shared__ float qh[HDIM];
    __shared__ float sc[SEQ];
    __shared__ float red1[8], red2[8];
    __shared__ float opart[16][HDIM];

    if (t < EMB) xlast[t] = x[((size_t)b*SEQ + SEQ-1)*EMB + t];
    __syncthreads();

    {
        int d = t & 31, c = t >> 5;            // c in 0..15
        const float* wr = Wq + (size_t)(h*HDIM + d)*EMB + c*16;
        float p = 0.f;
        #pragma unroll
        for (int j = 0; j < 16; j++) p += xlast[c*16 + j]*wr[j];
        qpart[d][c] = p;
    }
    __syncthreads();
    if (t < HDIM) {
        float qv = bq[h*HDIM + t];
        #pragma unroll
        for (int c = 0; c < 16; c++) qv += qpart[t][c];
        qh[t] = qv;
    }
    __syncthreads();

    // score for key t (this head only)
    {
        const __hip_bfloat16* krow = kbuf + ((size_t)b*SEQ + t)*EMB + h*HDIM;
        float s = 0.f;
        #pragma unroll
        for (int vv = 0; vv < 4; vv++) {
            short8 kk = *(const short8*)(krow + vv*8);
            #pragma unroll
            for (int j = 0; j < 8; j++)
                s += qh[vv*8 + j]*__bfloat162float(((const __hip_bfloat16*)&kk)[j]);
        }
        s *= 0.17677669529663687f;
        if (t == SEQ-1) s += -1e9f;
        sc[t] = s;
    }
    __syncthreads();

    // block softmax over 512 scores (8 waves)
    {
        int wv = t >> 6, lane = t & 63;
        float m = sc[t];
        #pragma unroll
        for (int o = 32; o; o >>= 1) m = fmaxf(m, __shfl_xor(m, o));
        if (lane == 0) red1[wv] = m;
        __syncthreads();
        m = red1[0];
        #pragma unroll
        for (int i = 1; i < 8; i++) m = fmaxf(m, red1[i]);
        float e = expf(sc[t] - m);
        float s = e;
        #pragma unroll
        for (int o = 32; o; o >>= 1) s += __shfl_xor(s, o);
        if (lane == 0) red2[wv] = s;
        __syncthreads();
        float tot = red2[0]+red2[1]+red2[2]+red2[3]+red2[4]+red2[5]+red2[6]+red2[7];
        float a = e / tot;
        sc[t] = a;
        amh[((size_t)b*NHEADS + h)*SEQ + t] = a;
    }
    __syncthreads();

    // o_last for this head's 32 dims: 16-way k-partition
    {
        int e = t & 31, part = t >> 5;
        float o = 0.f;
        const __hip_bfloat16* vc = vbuf + (size_t)b*SEQ*EMB + h*HDIM + e;
        for (int k = part*32; k < part*32 + 32; k++)
            o += sc[k]*__bfloat162float(vc[(size_t)k*EMB]);
        opart[part][e] = o;
    }
    __syncthreads();
    if (t < HDIM) {
        float o = 0.f;
        #pragma unroll
        for (int p = 0; p < 16; p++) o += opart[p][t];
        vbuf[((size_t)b*SEQ + SEQ-1)*EMB + h*HDIM + t] = __float2bfloat16(o);
    }
}

// ---------------- write full attns output [L,B,S,S]; head-avg fused for last rows ----------------
__global__ void write_attns(float* __restrict__ attns, const float* __restrict__ amh_all)
{
    constexpr int PER_ROW = SEQ/4;
    size_t tid = (size_t)blockIdx.x*blockDim.x + threadIdx.x;
    size_t row = tid / PER_ROW;
    int c4 = (int)(tid % PER_ROW);
    int q = (int)(row % SEQ);
    float4 v = make_float4(0.f,0.f,0.f,0.f);
    if (q == SEQ-1) {
        size_t lb = row / SEQ;
        const float* base = amh_all + lb*NHEADS*SEQ + c4*4;
        float x0=0.f, x1=0.f, x2=0.f, x3=0.f;
        #pragma unroll
        for (int h = 0; h < NHEADS; h++) {
            const float* r = base + (size_t)h*SEQ;
            x0 += r[0]; x1 += r[1]; x2 += r[2]; x3 += r[3];
        }
        v = make_float4(x0*0.125f, x1*0.125f, x2*0.125f, x3*0.125f);
    } else if ((q >> 2) == c4) {
        ((float*)&v)[q & 3] = 1.f;
    }
    ((float4*)attns)[tid] = v;
}

// ---------------- partial relu-sum over sequence chunks ----------------
__global__ void reduce_relu_part(const float* __restrict__ x, float* __restrict__ rp)
{
    int b = blockIdx.x, ch = blockIdx.y, e = threadIdx.x;
    const float* xb = x + ((size_t)b*SEQ + ch*(SEQ/8))*EMB;
    float s = 0.f;
    for (int i = 0; i < SEQ/8; i++) s += fmaxf(xb[(size_t)i*EMB + e], 0.f);
    rp[(b*8 + ch)*EMB + e] = s;
}

// ---------------- parallel decode + log_softmax: one block per batch row ----------------
__global__ __launch_bounds__(256)
void decode_out2(const float* __restrict__ rp, const float* __restrict__ dec_W,
                 float* __restrict__ out)
{
    int b = blockIdx.x, t = threadIdx.x;
    float r = 0.f;
    #pragma unroll
    for (int ch = 0; ch < 8; ch++) r += rp[(b*8 + ch)*EMB + t];
    float part[NCLS];
    #pragma unroll
    for (int c = 0; c < NCLS; c++) part[c] = r * dec_W[c*EMB + t];
    #pragma unroll
    for (int o = 32; o; o >>= 1)
        #pragma unroll
        for (int c = 0; c < NCLS; c++) part[c] += __shfl_xor(part[c], o);
    __shared__ float red[4][NCLS];
    int wv = t >> 6, lane = t & 63;
    if (lane == 0)
        #pragma unroll
        for (int c = 0; c < NCLS; c++) red[wv][c] = part[c];
    __syncthreads();
    if (t == 0) {
        float lg[NCLS];
        float m = -1e30f;
        #pragma unroll
        for (int c = 0; c < NCLS; c++) {
            lg[c] = (red[0][c]+red[1][c]+red[2][c]+red[3][c]) * (1.f/(float)SEQ);
            m = fmaxf(m, lg[c]);
        }
        float s = 0.f;
        #pragma unroll
        for (int c = 0; c < NCLS; c++) s += expf(lg[c] - m);
        float ls = logf(s);
        #pragma unroll
        for (int c = 0; c < NCLS; c++) out[b*NCLS + c] = lg[c] - m - ls;
    }
}

} // namespace

extern "C" void kernel_launch(void* const* d_in, const int* in_sizes, int n_in,
                              void* d_out, int out_size, void* d_ws, size_t ws_size,
                              hipStream_t stream)
{
    const float* src   = (const float*)d_in[0];
    const float* emb_W = (const float*)d_in[1];
    const float* emb_b = (const float*)d_in[2];
    const float* Wqkv  = (const float*)d_in[3];
    const float* bqkv  = (const float*)d_in[4];
    const float* Wo    = (const float*)d_in[5];
    const float* bo    = (const float*)d_in[6];
    const float* ln1_g = (const float*)d_in[7];
    const float* ln1_b = (const float*)d_in[8];
    const float* ln2_g = (const float*)d_in[9];
    const float* ln2_b = (const float*)d_in[10];
    const float* W1    = (const float*)d_in[11];
    const float* b1    = (const float*)d_in[12];
    const float* W2    = (const float*)d_in[13];
    const float* b2    = (const float*)d_in[14];
    const float* dec_W = (const float*)d_in[15];

    float* out   = (float*)d_out;               // [32,10]
    float* attns = out + BATCH*NCLS;            // [4,32,512,512]

    // workspace layout (~84 MB), no aliasing
    char* ws = (char*)d_ws;
    float*          xbuf = (float*)ws;              ws += (size_t)NTOK*EMB*4;     // 16.78 MB
    __hip_bfloat16* xb16 = (__hip_bfloat16*)ws;     ws += (size_t)NTOK*EMB*2;     //  8.39 MB
    __hip_bfloat16* kbuf = (__hip_bfloat16*)ws;     ws += (size_t)NTOK*EMB*2;     //  8.39 MB
    __hip_bfloat16* vbuf = (__hip_bfloat16*)ws;     ws += (size_t)NTOK*EMB*2;     //  8.39 MB
    __hip_bfloat16* hbuf = (__hip_bfloat16*)ws;     ws += (size_t)NTOK*FF*2;      // 33.55 MB
    __hip_bfloat16* wq16 = (__hip_bfloat16*)ws;     ws += (size_t)NLAYER*3*EMB*EMB*2;
    __hip_bfloat16* wo16 = (__hip_bfloat16*)ws;     ws += (size_t)NLAYER*EMB*EMB*2;
    __hip_bfloat16* w116 = (__hip_bfloat16*)ws;     ws += (size_t)NLAYER*FF*EMB*2;
    __hip_bfloat16* w216 = (__hip_bfloat16*)ws;     ws += (size_t)NLAYER*EMB*FF*2;
    float*          amall= (float*)ws;              ws += (size_t)NLAYER*BATCH*NHEADS*SEQ*4; // 2.1 MB
    float*          rpart= (float*)ws;              ws += BATCH*8*EMB*4;

    // weight conversion fp32 -> bf16
    f2b<<<NLAYER*3*EMB*EMB/4/256, 256, 0, stream>>>(Wqkv, wq16, NLAYER*3*EMB*EMB);
    f2b<<<NLAYER*EMB*EMB/4/256,   256, 0, stream>>>(Wo,   wo16, NLAYER*EMB*EMB);
    f2b<<<NLAYER*FF*EMB/4/256,    256, 0, stream>>>(W1,   w116, NLAYER*FF*EMB);
    f2b<<<NLAYER*EMB*FF/4/256,    256, 0, stream>>>(W2,   w216, NLAYER*EMB*FF);

    embed_kernel<<<NTOK, EMB, 0, stream>>>(src, emb_W, emb_b, xbuf, xb16);

    for (int l = 0; l < NLAYER; l++) {
        const __hip_bfloat16* wql = wq16 + (size_t)l*3*EMB*EMB;
        const float* bql = bqkv + (size_t)l*3*EMB;

        // fused k|v projection: N=512 over W rows [E..3E)
        gemm_mfma<false, true><<<dim3(512/128, NTOK/128), 256, 0, stream>>>(
            xb16, EMB, wql + (size_t)EMB*EMB, bql + EMB, kbuf, vbuf, EMB, EMB);

        // fused per-(b,h): q GEMV + scores + softmax + per-head row + o_last
        attn_last_head<<<dim3(NHEADS, BATCH), 512, 0, stream>>>(
            xbuf, Wqkv + (size_t)l*3*EMB*EMB, bqkv + (size_t)l*3*EMB,
            kbuf, vbuf, amall + (size_t)l*BATCH*NHEADS*SEQ);

        // Wo GEMM + bias + residual + LN1 (writes xbuf/xb16)
        gemm_ln<<<NTOK/64, 256, 0, stream>>>(
            vbuf, EMB, wo16 + (size_t)l*EMB*EMB, bo + (size_t)l*EMB,
            ln1_g + l*EMB, ln1_b + l*EMB, xbuf, xb16, EMB);

        // FFN1 (relu, bf16 out)
        gemm_mfma<true, false><<<dim3(FF/128, NTOK/128), 256, 0, stream>>>(
            xb16, EMB, w116 + (size_t)l*FF*EMB, b1 + (size_t)l*FF, hbuf, nullptr, FF, EMB);

        // FFN2 GEMM + bias + residual + LN2
        gemm_ln<<<NTOK/64, 256, 0, stream>>>(
            hbuf, FF, w216 + (size_t)l*EMB*FF, b2 + (size_t)l*EMB,
            ln2_g + l*EMB, ln2_b + l*EMB, xbuf, xb16, FF);
    }

    {
        size_t total_f4 = (size_t)NLAYER*BATCH*SEQ*(SEQ/4);
        int blocks = (int)((total_f4 + 255)/256);
        write_attns<<<blocks, 256, 0, stream>>>(attns, amall);
    }

    reduce_relu_part<<<dim3(BATCH, 8), EMB, 0, stream>>>(xbuf, rpart);
    decode_out2<<<BATCH, 256, 0, stream>>>(rpart, dec_W, out);
}

// Round 9
// 553.982 us; speedup vs baseline: 8.6711x; 1.1194x over previous
//
#include <hip/hip_runtime.h>
#include <hip/hip_bf16.h>
#include <math.h>

namespace {

constexpr int BATCH = 32;
constexpr int SEQ   = 512;
constexpr int DIN   = 9;
constexpr int EMB   = 256;
constexpr int FF    = 1024;
constexpr int NLAYER= 4;
constexpr int NCLS  = 10;
constexpr int NHEADS= 8;
constexpr int HDIM  = 32;
constexpr int NTOK  = BATCH*SEQ;      // 16384

typedef __attribute__((ext_vector_type(8))) short short8;
typedef __attribute__((ext_vector_type(4))) float floatx4;

#define GLOAD_LDS16(g, l) __builtin_amdgcn_global_load_lds( \
    (const __attribute__((address_space(1))) unsigned*)(g), \
    (__attribute__((address_space(3))) unsigned*)(l), 16, 0, 0)

// ---------------- bf16 MFMA GEMM, 2-phase double-buffered ----------------
// C[M,N] = A[M,K] @ W[N,K]^T + bias. 128x128 tile, BK=32, 4 waves (2x2).
// KV=true: N=512 fused k|v projection — block col bn<256 -> C0 (k), else C1 (v).
template<bool RELU, bool KV>
__global__ __launch_bounds__(256)
void gemm_mfma(const __hip_bfloat16* __restrict__ A, int lda,
               const __hip_bfloat16* __restrict__ W,     // [N,K] row-major
               const float* __restrict__ bias,
               __hip_bfloat16* __restrict__ C0,
               __hip_bfloat16* __restrict__ C1,
               int ldc, int K)
{
    __shared__ __hip_bfloat16 As[2*128*32];
    __shared__ __hip_bfloat16 Bs[2*128*32];
    const int bm = blockIdx.y*128, bn = blockIdx.x*128;
    const int tid  = threadIdx.x;
    const int lane = tid & 63;
    const int w    = tid >> 6;
    const int wm   = (w >> 1)*64, wn = (w & 1)*64;

    floatx4 acc[4][4] = {};

    const int srow = w*32 + (lane >> 2);
    const int scol = (lane & 3)*8;
    const __hip_bfloat16* gA0 = A + (size_t)(bm + srow)*lda + scol;
    const __hip_bfloat16* gA1 = A + (size_t)(bm + srow + 16)*lda + scol;
    const __hip_bfloat16* gB0 = W + (size_t)(bn + srow)*K + scol;
    const __hip_bfloat16* gB1 = W + (size_t)(bn + srow + 16)*K + scol;
    const int l0 = (w*2)*512, l1 = (w*2 + 1)*512;

#define GM_STAGE(buf, k0) do { \
    GLOAD_LDS16(gA0 + (k0), As + (buf)*4096 + l0); \
    GLOAD_LDS16(gA1 + (k0), As + (buf)*4096 + l1); \
    GLOAD_LDS16(gB0 + (k0), Bs + (buf)*4096 + l0); \
    GLOAD_LDS16(gB1 + (k0), Bs + (buf)*4096 + l1); } while (0)

    const int arow = wm + (lane & 15);
    const int brow = wn + (lane & 15);
    const int kh   = lane >> 4;
    const int nt   = K >> 5;

    GM_STAGE(0, 0);
    __syncthreads();
    for (int t = 0; t < nt; t++) {
        const int cur = t & 1;
        if (t + 1 < nt) GM_STAGE(cur ^ 1, (t+1)*32);   // issue next-tile loads early
        const short8* Ab = (const short8*)(As + cur*4096);
        const short8* Bb = (const short8*)(Bs + cur*4096);
        short8 af[4], bf[4];
        #pragma unroll
        for (int m = 0; m < 4; m++) af[m] = Ab[(arow + m*16)*4 + kh];
        #pragma unroll
        for (int n = 0; n < 4; n++) bf[n] = Bb[(brow + n*16)*4 + kh];
        #pragma unroll
        for (int m = 0; m < 4; m++)
            #pragma unroll
            for (int n = 0; n < 4; n++)
                acc[m][n] = __builtin_amdgcn_mfma_f32_16x16x32_bf16(af[m], bf[n], acc[m][n], 0, 0, 0);
        __syncthreads();
    }
#undef GM_STAGE

    __hip_bfloat16* Cb;
    int cb;
    if (KV && bn >= 256) { Cb = C1; cb = bn - 256; }
    else                 { Cb = C0; cb = bn; }

    const int crow0 = bm + wm + (lane >> 4)*4;
    #pragma unroll
    for (int n = 0; n < 4; n++) {
        const int coln = wn + (lane & 15) + n*16;
        const float bv = bias[bn + coln];
        #pragma unroll
        for (int m = 0; m < 4; m++) {
            #pragma unroll
            for (int r = 0; r < 4; r++) {
                int row = crow0 + m*16 + r;
                float v = acc[m][n][r] + bv;
                if (RELU) v = fmaxf(v, 0.f);
                Cb[(size_t)row*ldc + cb + coln] = __float2bfloat16(v);
            }
        }
    }
}

// ---------------- fused GEMM + bias + residual + LayerNorm, split-K x2 ----------------
// C[M,256] = A[M,K] @ W[256,K]^T + bias; xnew = LN(xres + C)*g + b.
// BM=32, 256 threads = 4 waves: w&1 = 16-row group, w>>1 = K-half.
// Each wave: acc[16] (16 rows x 256 cols) over its K-half. Epilogue: half-1
// waves dump acc to LDS; half-0 waves reduce + bias + residual + wave-local LN.
// Grid = NTOK/32 = 512 blocks -> 2 blocks/CU, 2 waves/SIMD.
__global__ __launch_bounds__(256)
void gemm_ln(const __hip_bfloat16* __restrict__ A, int lda,
             const __hip_bfloat16* __restrict__ W,     // [256,K]
             const float* __restrict__ bias,
             const float* __restrict__ g,
             const float* __restrict__ bb,
             float* __restrict__ xres,                 // in/out fp32 [NTOK,256]
             __hip_bfloat16* __restrict__ xb16,        // out bf16 mirror
             int K)
{
    // [dbuf][ A: 2half x 32r x 32k (2048) | B: 2half x 256r x 32k (16384) ] bf16 = 72 KB
    __shared__ __hip_bfloat16 SM[2][18432];
    const int bm  = blockIdx.x*32;
    const int tid = threadIdx.x;
    const int lane= tid & 63;
    const int w   = tid >> 6;
    const int rgrp= w & 1;
    const int half= w >> 1;
    const int cl  = lane & 15;
    const int rg  = lane >> 4;
    const int Kh  = K >> 1;

    floatx4 acc[16] = {};

    // 36 staging chunks of 1KB: ids 0-3 = A(h=id>>1, rc=id&1); 4-35 = B(h=(id-4)>>4, rc=(id-4)&15)
    const __hip_bfloat16* gsrc[9];
    int loff[9];
    #pragma unroll
    for (int i = 0; i < 9; i++) {
        int id = w*9 + i;
        if (id < 4) {
            int h = id >> 1, rc = id & 1;
            gsrc[i] = A + (size_t)(bm + rc*16 + (lane >> 2))*lda + h*Kh + (lane & 3)*8;
            loff[i] = h*1024 + rc*512;
        } else {
            int idb = id - 4;
            int h = idb >> 4, rc = idb & 15;
            gsrc[i] = W + (size_t)(rc*16 + (lane >> 2))*K + h*Kh + (lane & 3)*8;
            loff[i] = 2048 + h*8192 + rc*512;
        }
    }

#define GL2_STAGE(buf, k0) do { \
    _Pragma("unroll") \
    for (int i = 0; i < 9; i++) GLOAD_LDS16(gsrc[i] + (k0), &SM[buf][loff[i]]); } while (0)

    const int nt = Kh >> 5;
    GL2_STAGE(0, 0);
    __syncthreads();
    const int aidx = half*128 + (rgrp*16 + cl)*4 + rg;
    for (int t = 0; t < nt; t++) {
        const int cur = t & 1;
        if (t + 1 < nt) GL2_STAGE(cur ^ 1, (t+1)*32);
        const short8* Sb = (const short8*)SM[cur];
        short8 af = Sb[aidx];
        #pragma unroll
        for (int n = 0; n < 16; n++) {
            short8 bf = Sb[256 + half*1024 + (n*16 + cl)*4 + rg];
            acc[n] = __builtin_amdgcn_mfma_f32_16x16x32_bf16(af, bf, acc[n], 0, 0, 0);
        }
        __syncthreads();
    }
#undef GL2_STAGE

    // cross-wave K reduction via LDS (lane-interleaved, conflict-free)
    float* R = (float*)SM;
    if (half == 1) {
        #pragma unroll
        for (int n = 0; n < 16; n++)
            #pragma unroll
            for (int r = 0; r < 4; r++)
                R[rgrp*4096 + (n*4 + r)*64 + lane] = acc[n][r];
    }
    __syncthreads();
    if (half == 0) {
        #pragma unroll
        for (int n = 0; n < 16; n++)
            #pragma unroll
            for (int r = 0; r < 4; r++)
                acc[n][r] += R[rgrp*4096 + (n*4 + r)*64 + lane];

        float bv[16], gv[16], bbv[16];
        #pragma unroll
        for (int n = 0; n < 16; n++) {
            const int c = n*16 + cl;
            bv[n] = bias[c]; gv[n] = g[c]; bbv[n] = bb[c];
        }
        #pragma unroll
        for (int r = 0; r < 4; r++) {
            const int row = bm + rgrp*16 + rg*4 + r;
            float* xr = xres + (size_t)row*EMB;
            __hip_bfloat16* xbr = xb16 + (size_t)row*EMB;
            float vals[16];
            float S = 0.f, Q = 0.f;
            #pragma unroll
            for (int n = 0; n < 16; n++) {
                float v = acc[n][r] + bv[n] + xr[n*16 + cl];
                vals[n] = v; S += v; Q += v*v;
            }
            #pragma unroll
            for (int o = 1; o < 16; o <<= 1) { S += __shfl_xor(S, o); Q += __shfl_xor(Q, o); }
            const float mean = S * (1.f/EMB);
            const float var  = Q * (1.f/EMB) - mean*mean;
            const float rstd = 1.f / sqrtf(var + 1e-5f);
            #pragma unroll
            for (int n = 0; n < 16; n++) {
                float v = (vals[n] - mean)*rstd*gv[n] + bbv[n];
                xr [n*16 + cl] = v;
                xbr[n*16 + cl] = __float2bfloat16(v);
            }
        }
    }
}

// ---------------- fused fp32 -> bf16 weight conversion (all 4 arrays, 1 launch) ----------------
// segments (in 1024-elem blocks): Wqkv 768 | Wo 256 | W1 1024 | W2 1024
__global__ void f2b_all(const float* __restrict__ s0, const float* __restrict__ s1,
                        const float* __restrict__ s2, const float* __restrict__ s3,
                        __hip_bfloat16* __restrict__ d0, __hip_bfloat16* __restrict__ d1,
                        __hip_bfloat16* __restrict__ d2, __hip_bfloat16* __restrict__ d3)
{
    int blk = blockIdx.x;
    const float* s; __hip_bfloat16* d; int base;
    if      (blk <  768) { s = s0; d = d0; base = blk; }
    else if (blk < 1024) { s = s1; d = d1; base = blk - 768; }
    else if (blk < 2048) { s = s2; d = d2; base = blk - 1024; }
    else                 { s = s3; d = d3; base = blk - 2048; }
    int i = (base*256 + threadIdx.x)*4;
    float4 v = *(const float4*)(s + i);
    __hip_bfloat16 tmp[4];
    tmp[0] = __float2bfloat16(v.x); tmp[1] = __float2bfloat16(v.y);
    tmp[2] = __float2bfloat16(v.z); tmp[3] = __float2bfloat16(v.w);
    *(ushort4*)(d + i) = *(const ushort4*)tmp;
}

// ---------------- embed + scale + pos-enc; writes fp32 + bf16 mirrors ----------------
__global__ void embed_kernel(const float* __restrict__ src,
                             const float* __restrict__ emb_W,
                             const float* __restrict__ emb_b,
                             float* __restrict__ x,
                             __hip_bfloat16* __restrict__ xb)
{
    int row = blockIdx.x;
    int e = threadIdx.x;
    int s = row % SEQ;
    const float* sr = src + (size_t)row*DIN;
    float acc = emb_b[e];
    #pragma unroll
    for (int d = 0; d < DIN; d++) acc += sr[d]*emb_W[e*DIN + d];
    acc *= 16.0f;                    // sqrt(EMB)
    int i2 = e & ~1;
    float div = expf(-(float)i2 * (9.210340371976184f / (float)EMB));
    float ang = (float)s * div;
    float pe = (e & 1) ? cosf(ang) : sinf(ang);
    float v = acc + pe;
    x [(size_t)row*EMB + e] = v;
    xb[(size_t)row*EMB + e] = __float2bfloat16(v);
}

// ---------------- per-(b,h) last-row attention (contiguous k/v buffers) ----------------
__global__ __launch_bounds__(512)
void attn_last_head(const float* __restrict__ x,          // [NTOK, EMB] fp32
                    const float* __restrict__ Wq,         // [EMB, EMB] (q rows of Wqkv[l])
                    const float* __restrict__ bq,
                    const __hip_bfloat16* __restrict__ kbuf, // [B*S,256]
                    __hip_bfloat16* __restrict__ vbuf,       // [B*S,256]
                    float* __restrict__ amh)              // [B*H, SEQ] for this layer
{
    const int h = blockIdx.x, b = blockIdx.y;
    const int t = threadIdx.x;                 // 0..511
    __shared__ float xlast[EMB];
    __shared__ float qpart[HDIM][17];
    __shared__ float qh[HDIM];
    __shared__ float sc[SEQ];
    __shared__ float red1[8], red2[8];
    __shared__ float opart[16][HDIM];

    if (t < EMB) xlast[t] = x[((size_t)b*SEQ + SEQ-1)*EMB + t];
    __syncthreads();

    {
        int d = t & 31, c = t >> 5;            // c in 0..15
        const float* wr = Wq + (size_t)(h*HDIM + d)*EMB + c*16;
        float p = 0.f;
        #pragma unroll
        for (int j = 0; j < 16; j++) p += xlast[c*16 + j]*wr[j];
        qpart[d][c] = p;
    }
    __syncthreads();
    if (t < HDIM) {
        float qv = bq[h*HDIM + t];
        #pragma unroll
        for (int c = 0; c < 16; c++) qv += qpart[t][c];
        qh[t] = qv;
    }
    __syncthreads();

    // score for key t (this head only)
    {
        const __hip_bfloat16* krow = kbuf + ((size_t)b*SEQ + t)*EMB + h*HDIM;
        float s = 0.f;
        #pragma unroll
        for (int vv = 0; vv < 4; vv++) {
            short8 kk = *(const short8*)(krow + vv*8);
            #pragma unroll
            for (int j = 0; j < 8; j++)
                s += qh[vv*8 + j]*__bfloat162float(((const __hip_bfloat16*)&kk)[j]);
        }
        s *= 0.17677669529663687f;
        if (t == SEQ-1) s += -1e9f;
        sc[t] = s;
    }
    __syncthreads();

    // block softmax over 512 scores (8 waves)
    {
        int wv = t >> 6, lane = t & 63;
        float m = sc[t];
        #pragma unroll
        for (int o = 32; o; o >>= 1) m = fmaxf(m, __shfl_xor(m, o));
        if (lane == 0) red1[wv] = m;
        __syncthreads();
        m = red1[0];
        #pragma unroll
        for (int i = 1; i < 8; i++) m = fmaxf(m, red1[i]);
        float e = expf(sc[t] - m);
        float s = e;
        #pragma unroll
        for (int o = 32; o; o >>= 1) s += __shfl_xor(s, o);
        if (lane == 0) red2[wv] = s;
        __syncthreads();
        float tot = red2[0]+red2[1]+red2[2]+red2[3]+red2[4]+red2[5]+red2[6]+red2[7];
        float a = e / tot;
        sc[t] = a;
        amh[((size_t)b*NHEADS + h)*SEQ + t] = a;
    }
    __syncthreads();

    // o_last for this head's 32 dims: 16-way k-partition
    {
        int e = t & 31, part = t >> 5;
        float o = 0.f;
        const __hip_bfloat16* vc = vbuf + (size_t)b*SEQ*EMB + h*HDIM + e;
        for (int k = part*32; k < part*32 + 32; k++)
            o += sc[k]*__bfloat162float(vc[(size_t)k*EMB]);
        opart[part][e] = o;
    }
    __syncthreads();
    if (t < HDIM) {
        float o = 0.f;
        #pragma unroll
        for (int p = 0; p < 16; p++) o += opart[p][t];
        vbuf[((size_t)b*SEQ + SEQ-1)*EMB + h*HDIM + t] = __float2bfloat16(o);
    }
}

// ---------------- write full attns output [L,B,S,S]; head-avg fused for last rows ----------------
__global__ void write_attns(float* __restrict__ attns, const float* __restrict__ amh_all)
{
    constexpr int PER_ROW = SEQ/4;
    size_t tid = (size_t)blockIdx.x*blockDim.x + threadIdx.x;
    size_t row = tid / PER_ROW;
    int c4 = (int)(tid % PER_ROW);
    int q = (int)(row % SEQ);
    float4 v = make_float4(0.f,0.f,0.f,0.f);
    if (q == SEQ-1) {
        size_t lb = row / SEQ;
        const float* base = amh_all + lb*NHEADS*SEQ + c4*4;
        float x0=0.f, x1=0.f, x2=0.f, x3=0.f;
        #pragma unroll
        for (int h = 0; h < NHEADS; h++) {
            const float* r = base + (size_t)h*SEQ;
            x0 += r[0]; x1 += r[1]; x2 += r[2]; x3 += r[3];
        }
        v = make_float4(x0*0.125f, x1*0.125f, x2*0.125f, x3*0.125f);
    } else if ((q >> 2) == c4) {
        ((float*)&v)[q & 3] = 1.f;
    }
    ((float4*)attns)[tid] = v;
}

// ---------------- partial relu-sum over sequence chunks ----------------
__global__ void reduce_relu_part(const float* __restrict__ x, float* __restrict__ rp)
{
    int b = blockIdx.x, ch = blockIdx.y, e = threadIdx.x;
    const float* xb = x + ((size_t)b*SEQ + ch*(SEQ/8))*EMB;
    float s = 0.f;
    for (int i = 0; i < SEQ/8; i++) s += fmaxf(xb[(size_t)i*EMB + e], 0.f);
    rp[(b*8 + ch)*EMB + e] = s;
}

// ---------------- parallel decode + log_softmax: one block per batch row ----------------
__global__ __launch_bounds__(256)
void decode_out2(const float* __restrict__ rp, const float* __restrict__ dec_W,
                 float* __restrict__ out)
{
    int b = blockIdx.x, t = threadIdx.x;
    float r = 0.f;
    #pragma unroll
    for (int ch = 0; ch < 8; ch++) r += rp[(b*8 + ch)*EMB + t];
    float part[NCLS];
    #pragma unroll
    for (int c = 0; c < NCLS; c++) part[c] = r * dec_W[c*EMB + t];
    #pragma unroll
    for (int o = 32; o; o >>= 1)
        #pragma unroll
        for (int c = 0; c < NCLS; c++) part[c] += __shfl_xor(part[c], o);
    __shared__ float red[4][NCLS];
    int wv = t >> 6, lane = t & 63;
    if (lane == 0)
        #pragma unroll
        for (int c = 0; c < NCLS; c++) red[wv][c] = part[c];
    __syncthreads();
    if (t == 0) {
        float lg[NCLS];
        float m = -1e30f;
        #pragma unroll
        for (int c = 0; c < NCLS; c++) {
            lg[c] = (red[0][c]+red[1][c]+red[2][c]+red[3][c]) * (1.f/(float)SEQ);
            m = fmaxf(m, lg[c]);
        }
        float s = 0.f;
        #pragma unroll
        for (int c = 0; c < NCLS; c++) s += expf(lg[c] - m);
        float ls = logf(s);
        #pragma unroll
        for (int c = 0; c < NCLS; c++) out[b*NCLS + c] = lg[c] - m - ls;
    }
}

} // namespace

extern "C" void kernel_launch(void* const* d_in, const int* in_sizes, int n_in,
                              void* d_out, int out_size, void* d_ws, size_t ws_size,
                              hipStream_t stream)
{
    const float* src   = (const float*)d_in[0];
    const float* emb_W = (const float*)d_in[1];
    const float* emb_b = (const float*)d_in[2];
    const float* Wqkv  = (const float*)d_in[3];
    const float* bqkv  = (const float*)d_in[4];
    const float* Wo    = (const float*)d_in[5];
    const float* bo    = (const float*)d_in[6];
    const float* ln1_g = (const float*)d_in[7];
    const float* ln1_b = (const float*)d_in[8];
    const float* ln2_g = (const float*)d_in[9];
    const float* ln2_b = (const float*)d_in[10];
    const float* W1    = (const float*)d_in[11];
    const float* b1    = (const float*)d_in[12];
    const float* W2    = (const float*)d_in[13];
    const float* b2    = (const float*)d_in[14];
    const float* dec_W = (const float*)d_in[15];

    float* out   = (float*)d_out;               // [32,10]
    float* attns = out + BATCH*NCLS;            // [4,32,512,512]

    // workspace layout (~84 MB), no aliasing
    char* ws = (char*)d_ws;
    float*          xbuf = (float*)ws;              ws += (size_t)NTOK*EMB*4;     // 16.78 MB
    __hip_bfloat16* xb16 = (__hip_bfloat16*)ws;     ws += (size_t)NTOK*EMB*2;     //  8.39 MB
    __hip_bfloat16* kbuf = (__hip_bfloat16*)ws;     ws += (size_t)NTOK*EMB*2;     //  8.39 MB
    __hip_bfloat16* vbuf = (__hip_bfloat16*)ws;     ws += (size_t)NTOK*EMB*2;     //  8.39 MB
    __hip_bfloat16* hbuf = (__hip_bfloat16*)ws;     ws += (size_t)NTOK*FF*2;      // 33.55 MB
    __hip_bfloat16* wq16 = (__hip_bfloat16*)ws;     ws += (size_t)NLAYER*3*EMB*EMB*2;
    __hip_bfloat16* wo16 = (__hip_bfloat16*)ws;     ws += (size_t)NLAYER*EMB*EMB*2;
    __hip_bfloat16* w116 = (__hip_bfloat16*)ws;     ws += (size_t)NLAYER*FF*EMB*2;
    __hip_bfloat16* w216 = (__hip_bfloat16*)ws;     ws += (size_t)NLAYER*EMB*FF*2;
    float*          amall= (float*)ws;              ws += (size_t)NLAYER*BATCH*NHEADS*SEQ*4; // 2.1 MB
    float*          rpart= (float*)ws;              ws += BATCH*8*EMB*4;

    // weight conversion fp32 -> bf16 (single launch)
    f2b_all<<<3072, 256, 0, stream>>>(Wqkv, Wo, W1, W2, wq16, wo16, w116, w216);

    embed_kernel<<<NTOK, EMB, 0, stream>>>(src, emb_W, emb_b, xbuf, xb16);

    for (int l = 0; l < NLAYER; l++) {
        const __hip_bfloat16* wql = wq16 + (size_t)l*3*EMB*EMB;
        const float* bql = bqkv + (size_t)l*3*EMB;

        // fused k|v projection: N=512 over W rows [E..3E)
        gemm_mfma<false, true><<<dim3(512/128, NTOK/128), 256, 0, stream>>>(
            xb16, EMB, wql + (size_t)EMB*EMB, bql + EMB, kbuf, vbuf, EMB, EMB);

        // fused per-(b,h): q GEMV + scores + softmax + per-head row + o_last
        attn_last_head<<<dim3(NHEADS, BATCH), 512, 0, stream>>>(
            xbuf, Wqkv + (size_t)l*3*EMB*EMB, bqkv + (size_t)l*3*EMB,
            kbuf, vbuf, amall + (size_t)l*BATCH*NHEADS*SEQ);

        // Wo GEMM + bias + residual + LN1 (writes xbuf/xb16)
        gemm_ln<<<NTOK/32, 256, 0, stream>>>(
            vbuf, EMB, wo16 + (size_t)l*EMB*EMB, bo + (size_t)l*EMB,
            ln1_g + l*EMB, ln1_b + l*EMB, xbuf, xb16, EMB);

        // FFN1 (relu, bf16 out)
        gemm_mfma<true, false><<<dim3(FF/128, NTOK/128), 256, 0, stream>>>(
            xb16, EMB, w116 + (size_t)l*FF*EMB, b1 + (size_t)l*FF, hbuf, nullptr, FF, EMB);

        // FFN2 GEMM + bias + residual + LN2
        gemm_ln<<<NTOK/32, 256, 0, stream>>>(
            hbuf, FF, w216 + (size_t)l*EMB*FF, b2 + (size_t)l*EMB,
            ln2_g + l*EMB, ln2_b + l*EMB, xbuf, xb16, FF);
    }

    {
        size_t total_f4 = (size_t)NLAYER*BATCH*SEQ*(SEQ/4);
        int blocks = (int)((total_f4 + 255)/256);
        write_attns<<<blocks, 256, 0, stream>>>(attns, amall);
    }

    reduce_relu_part<<<dim3(BATCH, 8), EMB, 0, stream>>>(xbuf, rpart);
    decode_out2<<<BATCH, 256, 0, stream>>>(rpart, dec_W, out);
}